// Round 1
// baseline (1048.608 us; speedup 1.0000x reference)
//
#include <hip/hip_runtime.h>
#include <hip/hip_bf16.h>
#include <math.h>

// Problem constants
#define BATCH 4096
#define INPUT_SIZE 256
#define LATENT 64
#define HIDDEN 512
#define ACTIONS 12
#define EXPERTS 8
#define GATE_H 128
#define IN_DIM (INPUT_SIZE + LATENT)   // 320
#define INTER (HIDDEN + LATENT)        // 576

// ---------------------------------------------------------------------------
// Kernel 1: Lipschitz row scaling: Wout[r,:] = W[r,:] * min(softplus(c)/sum|W[r,:]|, 1)
// one wave (64 threads) per row
// ---------------------------------------------------------------------------
__global__ void scale_rows_kernel(const float* __restrict__ W,
                                  const float* __restrict__ cc,
                                  float* __restrict__ Wout, int cols) {
    const int row = blockIdx.x;
    const float* w = W + (size_t)row * cols;
    float s = 0.f;
    for (int i = threadIdx.x; i < cols; i += 64) s += fabsf(w[i]);
    #pragma unroll
    for (int off = 32; off > 0; off >>= 1) s += __shfl_down(s, off, 64);
    s = __shfl(s, 0, 64);
    const float cv = cc[0];
    // stable softplus
    const float lipc = (cv > 0.f) ? (cv + log1pf(expf(-cv))) : log1pf(expf(cv));
    const float scale = fminf(lipc / s, 1.0f);
    float* o = Wout + (size_t)row * cols;
    for (int i = threadIdx.x; i < cols; i += 64) o[i] = w[i] * scale;
}

// ---------------------------------------------------------------------------
// Kernel 2: gate MLP per sample: x(320) -> elu(128) -> elu(128) -> softmax(8)
// one block of 128 threads per sample
// ---------------------------------------------------------------------------
__global__ __launch_bounds__(128) void gate_forward_kernel(
    const float* __restrict__ z, const float* __restrict__ c,
    const float* __restrict__ W0, const float* __restrict__ b0,
    const float* __restrict__ W1, const float* __restrict__ b1,
    const float* __restrict__ W2, const float* __restrict__ b2,
    float* __restrict__ coeff) {
    __shared__ float x[IN_DIM];
    __shared__ float h[GATE_H];
    __shared__ float red[EXPERTS];

    const int b = blockIdx.x;
    const int t = threadIdx.x;

    if (t < LATENT) x[t] = z[(size_t)b * LATENT + t];
    for (int i = t; i < INPUT_SIZE; i += 128) x[LATENT + i] = c[(size_t)b * INPUT_SIZE + i];
    __syncthreads();

    // layer 0: 320 -> 128
    {
        const float* w = W0 + (size_t)t * IN_DIM;
        float acc = b0[t];
        #pragma unroll 4
        for (int i = 0; i < IN_DIM; ++i) acc = fmaf(x[i], w[i], acc);
        float hv = acc > 0.f ? acc : expm1f(acc);
        __syncthreads();
        h[t] = hv;
        __syncthreads();
    }
    // layer 1: 128 -> 128
    {
        const float* w = W1 + (size_t)t * GATE_H;
        float acc = b1[t];
        #pragma unroll 4
        for (int i = 0; i < GATE_H; ++i) acc = fmaf(h[i], w[i], acc);
        float hv = acc > 0.f ? acc : expm1f(acc);
        __syncthreads();
        h[t] = hv;
        __syncthreads();
    }
    // logits + softmax
    if (t < EXPERTS) {
        const float* w = W2 + (size_t)t * GATE_H;
        float acc = b2[t];
        #pragma unroll 4
        for (int i = 0; i < GATE_H; ++i) acc = fmaf(h[i], w[i], acc);
        red[t] = acc;
    }
    __syncthreads();
    if (t == 0) {
        float m = red[0];
        #pragma unroll
        for (int i = 1; i < EXPERTS; ++i) m = fmaxf(m, red[i]);
        float e[EXPERTS];
        float s = 0.f;
        #pragma unroll
        for (int i = 0; i < EXPERTS; ++i) { e[i] = expf(red[i] - m); s += e[i]; }
        const float inv = 1.f / s;
        #pragma unroll
        for (int i = 0; i < EXPERTS; ++i) coeff[(size_t)b * EXPERTS + i] = e[i] * inv;
    }
}

// ---------------------------------------------------------------------------
// Kernel 3: MoE layer.
// out[b,o] = act( sum_e coeff[b,e] * ( dot(inp[b,:], W[e,:,o]) + bias[e,o] ) )
// inp[b,i] = z[b,i] (i<64) else prev[b,i-64]
// Tiling: BM=64 samples x BN outputs per block, 256 threads, 4xTN micro-tile.
// Per K-chunk (BK=16): stage A-tile once + all 8 expert B-tiles in LDS;
// coeff-mix is linear so per-chunk expert partials accumulate exactly.
// ---------------------------------------------------------------------------
#define BM 64
#define BK 16

template<int IN, int PREV, int OUT, int BN, int TN, bool ACT>
__global__ __launch_bounds__(256) void moe_layer_kernel(
    const float* __restrict__ z, const float* __restrict__ prev,
    const float* __restrict__ W, const float* __restrict__ bias,
    const float* __restrict__ coeff, float* __restrict__ out) {

    __shared__ float As[BM][BK + 1];           // +1 pad: conflict-free r-strided reads
    __shared__ float Bs[EXPERTS][BK][BN];
    __shared__ float Cs[BM][EXPERTS];

    const int t  = threadIdx.x;
    const int b0 = blockIdx.x * BM;
    const int n0 = blockIdx.y * BN;
    const int tx = t & 15;
    const int ty = t >> 4;
    const int r0 = ty * 4;
    const int c0 = tx * TN;

    for (int idx = t; idx < BM * EXPERTS; idx += 256)
        Cs[idx >> 3][idx & 7] = coeff[(size_t)(b0 + (idx >> 3)) * EXPERTS + (idx & 7)];

    float facc[4][TN];
    #pragma unroll
    for (int i = 0; i < 4; ++i)
        #pragma unroll
        for (int j = 0; j < TN; ++j) facc[i][j] = 0.f;

    for (int k0 = 0; k0 < IN; k0 += BK) {
        __syncthreads();
        // stage A (BM x BK), coalesced along k
        #pragma unroll
        for (int idx = t; idx < BM * BK; idx += 256) {
            const int r  = idx >> 4;
            const int kk = idx & 15;
            const int col = k0 + kk;
            const float v = (col < LATENT)
                ? z[(size_t)(b0 + r) * LATENT + col]
                : prev[(size_t)(b0 + r) * PREV + (col - LATENT)];
            As[r][kk] = v;
        }
        // stage B for all experts (E x BK x BN), coalesced along out-col
        for (int idx = t; idx < EXPERTS * BK * BN; idx += 256) {
            const int cc2 = idx % BN;
            const int kk  = (idx / BN) % BK;
            const int e   = idx / (BN * BK);
            const int col = n0 + cc2;
            Bs[e][kk][cc2] = (col < OUT)
                ? W[((size_t)e * IN + (k0 + kk)) * OUT + col] : 0.f;
        }
        __syncthreads();

        #pragma unroll 1
        for (int e = 0; e < EXPERTS; ++e) {
            float cp[4][TN];
            #pragma unroll
            for (int i = 0; i < 4; ++i)
                #pragma unroll
                for (int j = 0; j < TN; ++j) cp[i][j] = 0.f;

            #pragma unroll
            for (int kk = 0; kk < BK; ++kk) {
                float a[4], bb[TN];
                #pragma unroll
                for (int i = 0; i < 4; ++i) a[i] = As[r0 + i][kk];
                #pragma unroll
                for (int j = 0; j < TN; ++j) bb[j] = Bs[e][kk][c0 + j];
                #pragma unroll
                for (int i = 0; i < 4; ++i)
                    #pragma unroll
                    for (int j = 0; j < TN; ++j)
                        cp[i][j] = fmaf(a[i], bb[j], cp[i][j]);
            }
            #pragma unroll
            for (int i = 0; i < 4; ++i) {
                const float ce = Cs[r0 + i][e];
                #pragma unroll
                for (int j = 0; j < TN; ++j)
                    facc[i][j] = fmaf(ce, cp[i][j], facc[i][j]);
            }
        }
    }

    // bias mix + activation + store
    #pragma unroll
    for (int i = 0; i < 4; ++i) {
        const int r = b0 + r0 + i;
        #pragma unroll
        for (int j = 0; j < TN; ++j) {
            const int col = n0 + c0 + j;
            if (col < OUT) {
                float bm = 0.f;
                #pragma unroll
                for (int e = 0; e < EXPERTS; ++e)
                    bm = fmaf(Cs[r0 + i][e], bias[(size_t)e * OUT + col], bm);
                float v = facc[i][j] + bm;
                if (ACT) v = v > 0.f ? v : expm1f(v);
                out[(size_t)r * OUT + col] = v;
            }
        }
    }
}

// ---------------------------------------------------------------------------
extern "C" void kernel_launch(void* const* d_in, const int* in_sizes, int n_in,
                              void* d_out, int out_size, void* d_ws, size_t ws_size,
                              hipStream_t stream) {
    const float* z   = (const float*)d_in[0];
    const float* c   = (const float*)d_in[1];
    const float* w0  = (const float*)d_in[2];
    const float* b0  = (const float*)d_in[3];
    const float* w1  = (const float*)d_in[4];
    const float* b1  = (const float*)d_in[5];
    const float* w2  = (const float*)d_in[6];
    const float* b2  = (const float*)d_in[7];
    const float* gw0 = (const float*)d_in[8];
    const float* gb0 = (const float*)d_in[9];
    const float* gc0 = (const float*)d_in[10];
    const float* gw1 = (const float*)d_in[11];
    const float* gb1 = (const float*)d_in[12];
    const float* gc1 = (const float*)d_in[13];
    const float* gw2 = (const float*)d_in[14];
    const float* gb2 = (const float*)d_in[15];
    const float* gc2 = (const float*)d_in[16];
    float* out = (float*)d_out;

    // workspace layout (floats)
    float* ws = (float*)d_ws;
    float* coeff = ws;                          // B*8        = 32768
    float* gW0s  = coeff + BATCH * EXPERTS;     // 128*320    = 40960
    float* gW1s  = gW0s + GATE_H * IN_DIM;      // 128*128    = 16384
    float* gW2s  = gW1s + GATE_H * GATE_H;      // 8*128      = 1024
    float* H1    = gW2s + EXPERTS * GATE_H;     // B*512
    float* H2    = H1 + (size_t)BATCH * HIDDEN; // B*512

    // 1) Lipschitz-scale gate weights
    scale_rows_kernel<<<GATE_H, 64, 0, stream>>>(gw0, gc0, gW0s, IN_DIM);
    scale_rows_kernel<<<GATE_H, 64, 0, stream>>>(gw1, gc1, gW1s, GATE_H);
    scale_rows_kernel<<<EXPERTS, 64, 0, stream>>>(gw2, gc2, gW2s, GATE_H);

    // 2) gate forward -> coeff (B x 8)
    gate_forward_kernel<<<BATCH, 128, 0, stream>>>(z, c, gW0s, gb0, gW1s, gb1,
                                                   gW2s, gb2, coeff);

    // 3) MoE layers
    dim3 g01(BATCH / BM, HIDDEN / 64);
    moe_layer_kernel<IN_DIM, INPUT_SIZE, HIDDEN, 64, 4, true>
        <<<g01, 256, 0, stream>>>(z, c, w0, b0, coeff, H1);
    moe_layer_kernel<INTER, HIDDEN, HIDDEN, 64, 4, true>
        <<<g01, 256, 0, stream>>>(z, H1, w1, b1, coeff, H2);
    dim3 g2(BATCH / BM, 1);
    moe_layer_kernel<INTER, HIDDEN, ACTIONS, 16, 1, false>
        <<<g2, 256, 0, stream>>>(z, H2, w2, b2, coeff, out);
}

// Round 2
// 519.727 us; speedup vs baseline: 2.0176x; 2.0176x over previous
//
#include <hip/hip_runtime.h>
#include <hip/hip_bf16.h>
#include <math.h>

#define BATCH 4096
#define INPUT_SIZE 256
#define LATENT 64
#define HIDDEN 512
#define ACTIONS 12
#define EXPERTS 8
#define GATE_H 128
#define IN_DIM (INPUT_SIZE + LATENT)   // 320
#define INTER (HIDDEN + LATENT)        // 576

typedef unsigned int u32;
typedef unsigned short u16;
typedef __attribute__((ext_vector_type(8))) short bf16x8;
typedef __attribute__((ext_vector_type(4))) float f32x4;

__device__ __forceinline__ u16 f2bf(float x) {
    u32 u = __float_as_uint(x);
    u32 r = (u + 0x7fffu + ((u >> 16) & 1u)) >> 16;
    return (u16)r;
}
__device__ __forceinline__ float bf2f(u16 h) { return __uint_as_float(((u32)h) << 16); }

__device__ __forceinline__ void gload16(const void* g, void* lds) {
    __builtin_amdgcn_global_load_lds(
        (const __attribute__((address_space(1))) u32*)g,
        (__attribute__((address_space(3))) u32*)lds, 16, 0, 0);
}

// ---------------------------------------------------------------------------
// Gate: Lipschitz row scaling (unchanged from round 0)
// ---------------------------------------------------------------------------
__global__ void scale_rows_kernel(const float* __restrict__ W,
                                  const float* __restrict__ cc,
                                  float* __restrict__ Wout, int cols) {
    const int row = blockIdx.x;
    const float* w = W + (size_t)row * cols;
    float s = 0.f;
    for (int i = threadIdx.x; i < cols; i += 64) s += fabsf(w[i]);
    #pragma unroll
    for (int off = 32; off > 0; off >>= 1) s += __shfl_down(s, off, 64);
    s = __shfl(s, 0, 64);
    const float cv = cc[0];
    const float lipc = (cv > 0.f) ? (cv + log1pf(expf(-cv))) : log1pf(expf(cv));
    const float scale = fminf(lipc / s, 1.0f);
    float* o = Wout + (size_t)row * cols;
    for (int i = threadIdx.x; i < cols; i += 64) o[i] = w[i] * scale;
}

// ---------------------------------------------------------------------------
// Gate MLP -> softmax coeff (unchanged from round 0, verified correct)
// ---------------------------------------------------------------------------
__global__ __launch_bounds__(128) void gate_forward_kernel(
    const float* __restrict__ z, const float* __restrict__ c,
    const float* __restrict__ W0, const float* __restrict__ b0,
    const float* __restrict__ W1, const float* __restrict__ b1,
    const float* __restrict__ W2, const float* __restrict__ b2,
    float* __restrict__ coeff) {
    __shared__ float x[IN_DIM];
    __shared__ float h[GATE_H];
    __shared__ float red[EXPERTS];

    const int b = blockIdx.x;
    const int t = threadIdx.x;

    if (t < LATENT) x[t] = z[(size_t)b * LATENT + t];
    for (int i = t; i < INPUT_SIZE; i += 128) x[LATENT + i] = c[(size_t)b * INPUT_SIZE + i];
    __syncthreads();
    {
        const float* w = W0 + (size_t)t * IN_DIM;
        float acc = b0[t];
        #pragma unroll 4
        for (int i = 0; i < IN_DIM; ++i) acc = fmaf(x[i], w[i], acc);
        float hv = acc > 0.f ? acc : expm1f(acc);
        __syncthreads();
        h[t] = hv;
        __syncthreads();
    }
    {
        const float* w = W1 + (size_t)t * GATE_H;
        float acc = b1[t];
        #pragma unroll 4
        for (int i = 0; i < GATE_H; ++i) acc = fmaf(h[i], w[i], acc);
        float hv = acc > 0.f ? acc : expm1f(acc);
        __syncthreads();
        h[t] = hv;
        __syncthreads();
    }
    if (t < EXPERTS) {
        const float* w = W2 + (size_t)t * GATE_H;
        float acc = b2[t];
        #pragma unroll 4
        for (int i = 0; i < GATE_H; ++i) acc = fmaf(h[i], w[i], acc);
        red[t] = acc;
    }
    __syncthreads();
    if (t == 0) {
        float m = red[0];
        #pragma unroll
        for (int i = 1; i < EXPERTS; ++i) m = fmaxf(m, red[i]);
        float e[EXPERTS];
        float s = 0.f;
        #pragma unroll
        for (int i = 0; i < EXPERTS; ++i) { e[i] = expf(red[i] - m); s += e[i]; }
        const float inv = 1.f / s;
        #pragma unroll
        for (int i = 0; i < EXPERTS; ++i) coeff[(size_t)b * EXPERTS + i] = e[i] * inv;
    }
}

// ---------------------------------------------------------------------------
// Weight prep: w (E, IN, OUT) f32 -> transposed split planes [OUTP][E*IN] bf16
// 64x64 LDS tile transpose per block. Rows OUT..OUTP-1 are zero-filled.
// ---------------------------------------------------------------------------
template<int IN, int OUT, int OUTP>
__global__ __launch_bounds__(256) void wprep_kernel(
    const float* __restrict__ w, u16* __restrict__ wthi, u16* __restrict__ wtlo) {
    __shared__ float tile[64][65];
    const int e  = blockIdx.x;
    const int i0 = blockIdx.y * 64;
    const int n0 = blockIdx.z * 64;
    const int t  = threadIdx.x;

    for (int idx = t; idx < 64 * 64; idx += 256) {
        const int r = idx >> 6, cc = idx & 63;
        tile[r][cc] = (n0 + cc < OUT)
            ? w[((size_t)e * IN + i0 + r) * OUT + n0 + cc] : 0.f;
    }
    __syncthreads();
    for (int idx = t; idx < 64 * 64; idx += 256) {
        const int r = idx >> 6, cc = idx & 63;      // r = n', cc = i'
        const float v = tile[cc][r];
        const size_t o = (size_t)(n0 + r) * (EXPERTS * IN) + (size_t)e * IN + i0 + cc;
        const u16 h = f2bf(v);
        wthi[o] = h;
        wtlo[o] = f2bf(v - bf2f(h));
    }
}

// ---------------------------------------------------------------------------
// A prep: x = [z | prev] row -> bf16 split planes xhi/xlo [B][IN]
// ---------------------------------------------------------------------------
template<int IN, int PREV>
__global__ __launch_bounds__(256) void amat_kernel(
    const float* __restrict__ z, const float* __restrict__ prev,
    u16* __restrict__ xhi, u16* __restrict__ xlo) {
    const int b = blockIdx.x;
    const int t = threadIdx.x;
    for (int i2 = t; i2 < IN / 2; i2 += 256) {
        const int i = i2 * 2;
        float v0, v1;
        if (i < LATENT) {
            v0 = z[(size_t)b * LATENT + i];
            v1 = z[(size_t)b * LATENT + i + 1];
        } else {
            v0 = prev[(size_t)b * PREV + i - LATENT];
            v1 = prev[(size_t)b * PREV + i + 1 - LATENT];
        }
        const u16 h0 = f2bf(v0), h1 = f2bf(v1);
        const u16 l0 = f2bf(v0 - bf2f(h0)), l1 = f2bf(v1 - bf2f(h1));
        ushort2 hh; hh.x = h0; hh.y = h1;
        ushort2 ll; ll.x = l0; ll.y = l1;
        ((ushort2*)xhi)[(size_t)b * (IN / 2) + i2] = hh;
        ((ushort2*)xlo)[(size_t)b * (IN / 2) + i2] = ll;
    }
}

// ---------------------------------------------------------------------------
// MoE GEMM: out[b,n] = act( sum_e coeff[b,e]*(x_b . W_e[:,n]) + sum_e coeff*bias )
// K per expert = 3*IN (split terms: hi*hi, hi*lo, lo*hi), e-outer in K.
// Tile 64x64, 4 waves (2x2), wave tile 32x32 via 16x16x32 bf16 MFMA.
// LDS XOR-swizzle (row&7)<<4 on both tiles; staged via global_load_lds with
// pre-swizzled global source (linear LDS dest). m97-style 2-barrier K-loop.
// ---------------------------------------------------------------------------
template<int IN, int OUT, bool ACT>
__global__ __launch_bounds__(256) void moe_gemm(
    const u16* __restrict__ Axhi, const u16* __restrict__ Axlo,
    const u16* __restrict__ Wthi, const u16* __restrict__ Wtlo,
    const float* __restrict__ bias, const float* __restrict__ coeff,
    float* __restrict__ out) {
    constexpr int NSTEP = (3 * IN) / 64;   // K-steps per expert
    constexpr int ESTR  = EXPERTS * IN;    // Wt row stride

    __shared__ u16 As[64 * 64];
    __shared__ u16 Bs[64 * 64];
    __shared__ float coeffS[64][EXPERTS];
    __shared__ float biasS[EXPERTS][64];

    const int t  = threadIdx.x;
    const int w  = t >> 6;
    const int l  = t & 63;
    const int b0 = blockIdx.x * 64;
    const int n0 = blockIdx.y * 64;
    const int wr = w >> 1, wc = w & 1;     // wave grid 2(m) x 2(n)

    for (int idx = t; idx < 64 * EXPERTS; idx += 256)
        coeffS[idx >> 3][idx & 7] = coeff[(size_t)(b0 + (idx >> 3)) * EXPERTS + (idx & 7)];
    for (int idx = t; idx < EXPERTS * 64; idx += 256) {
        const int e = idx >> 6, n = idx & 63;
        biasS[e][n] = (n0 + n < OUT) ? bias[e * OUT + n0 + n] : 0.f;
    }

    // staging lane decomposition: 64 lanes = 8 rows x 8 x 16B-blocks
    const int srow  = l >> 3;
    const int sblk8 = ((l & 7) ^ srow) * 8;   // pre-swizzled source offset (elements)

    // frag-read lane decomposition
    const int arow = l & 15;
    const int kgrp = l >> 4;                   // 0..3
    const int swz  = (l & 7) << 4;             // XOR key, rows here have row&7 == l&7

    f32x4 accF[2][2], accE[2][2];
    #pragma unroll
    for (int m = 0; m < 2; ++m) {
        accF[m][0] = (f32x4)0.f; accF[m][1] = (f32x4)0.f;
    }

    #pragma unroll 1
    for (int e = 0; e < EXPERTS; ++e) {
        #pragma unroll
        for (int m = 0; m < 2; ++m) { accE[m][0] = (f32x4)0.f; accE[m][1] = (f32x4)0.f; }

        #pragma unroll 1
        for (int ks = 0; ks < NSTEP; ++ks) {
            const int s  = (ks * 64) / IN;       // 0,1,2 (IN % 64 == 0)
            const int i0 = ks * 64 - s * IN;
            const u16* Ap = (s == 2) ? Axlo : Axhi;
            const u16* Bp = (s == 1) ? Wtlo : Wthi;

            __syncthreads();   // all waves done reading previous tiles
            #pragma unroll
            for (int p = 0; p < 2; ++p) {        // A: 64 rows, 8 per pass per wave
                const int r = 16 * w + 8 * p + srow;
                gload16(Ap + (size_t)(b0 + r) * IN + i0 + sblk8,
                        As + (16 * w + 8 * p) * 64);
            }
            #pragma unroll
            for (int p = 0; p < 2; ++p) {        // B: 64 rows
                const int r = 16 * w + 8 * p + srow;
                gload16(Bp + (size_t)(n0 + r) * ESTR + e * IN + i0 + sblk8,
                        Bs + (16 * w + 8 * p) * 64);
            }
            __syncthreads();   // drains vmcnt(0): staged tiles visible

            #pragma unroll
            for (int kk2 = 0; kk2 < 2; ++kk2) {
                const int kb = kk2 * 64 + kgrp * 16;
                bf16x8 bfr[2];
                #pragma unroll
                for (int n = 0; n < 2; ++n) {
                    const int row = wc * 32 + n * 16 + arow;
                    bfr[n] = *(const bf16x8*)((const char*)Bs + row * 128 + (kb ^ swz));
                }
                #pragma unroll
                for (int m = 0; m < 2; ++m) {
                    const int row = wr * 32 + m * 16 + arow;
                    const bf16x8 afr = *(const bf16x8*)((const char*)As + row * 128 + (kb ^ swz));
                    accE[m][0] = __builtin_amdgcn_mfma_f32_16x16x32_bf16(afr, bfr[0], accE[m][0], 0, 0, 0);
                    accE[m][1] = __builtin_amdgcn_mfma_f32_16x16x32_bf16(afr, bfr[1], accE[m][1], 0, 0, 0);
                }
            }
        }

        // fold expert e into final accumulator with per-row coeff
        #pragma unroll
        for (int m = 0; m < 2; ++m) {
            #pragma unroll
            for (int reg = 0; reg < 4; ++reg) {
                const float cv = coeffS[wr * 32 + m * 16 + kgrp * 4 + reg][e];
                accF[m][0][reg] += cv * accE[m][0][reg];
                accF[m][1][reg] += cv * accE[m][1][reg];
            }
        }
    }

    // epilogue: bias mix + activation + store
    #pragma unroll
    for (int m = 0; m < 2; ++m) {
        #pragma unroll
        for (int n = 0; n < 2; ++n) {
            #pragma unroll
            for (int reg = 0; reg < 4; ++reg) {
                const int row = wr * 32 + m * 16 + kgrp * 4 + reg;
                const int col = wc * 32 + n * 16 + arow;
                if (OUT == HIDDEN || n0 + col < OUT) {
                    float bm = 0.f;
                    #pragma unroll
                    for (int e = 0; e < EXPERTS; ++e)
                        bm = fmaf(coeffS[row][e], biasS[e][col], bm);
                    float v = accF[m][n][reg] + bm;
                    if (ACT) v = v > 0.f ? v : expm1f(v);
                    out[(size_t)(b0 + row) * OUT + n0 + col] = v;
                }
            }
        }
    }
}

// ---------------------------------------------------------------------------
extern "C" void kernel_launch(void* const* d_in, const int* in_sizes, int n_in,
                              void* d_out, int out_size, void* d_ws, size_t ws_size,
                              hipStream_t stream) {
    const float* z   = (const float*)d_in[0];
    const float* c   = (const float*)d_in[1];
    const float* w0  = (const float*)d_in[2];
    const float* b0  = (const float*)d_in[3];
    const float* w1  = (const float*)d_in[4];
    const float* b1  = (const float*)d_in[5];
    const float* w2  = (const float*)d_in[6];
    const float* b2  = (const float*)d_in[7];
    const float* gw0 = (const float*)d_in[8];
    const float* gb0 = (const float*)d_in[9];
    const float* gc0 = (const float*)d_in[10];
    const float* gw1 = (const float*)d_in[11];
    const float* gb1 = (const float*)d_in[12];
    const float* gc1 = (const float*)d_in[13];
    const float* gw2 = (const float*)d_in[14];
    const float* gb2 = (const float*)d_in[15];
    const float* gc2 = (const float*)d_in[16];
    float* out = (float*)d_out;

    // workspace layout
    char* p = (char*)d_ws;
    float* coeff = (float*)p;            p += (size_t)BATCH * EXPERTS * 4;
    float* gW0s  = (float*)p;            p += (size_t)GATE_H * IN_DIM * 4;
    float* gW1s  = (float*)p;            p += (size_t)GATE_H * GATE_H * 4;
    float* gW2s  = (float*)p;            p += (size_t)EXPERTS * GATE_H * 4;
    float* H1    = (float*)p;            p += (size_t)BATCH * HIDDEN * 4;
    float* H2    = (float*)p;            p += (size_t)BATCH * HIDDEN * 4;
    u16* xhi     = (u16*)p;              p += (size_t)BATCH * INTER * 2;
    u16* xlo     = (u16*)p;              p += (size_t)BATCH * INTER * 2;
    u16* wt0hi   = (u16*)p;              p += (size_t)HIDDEN * EXPERTS * IN_DIM * 2;
    u16* wt0lo   = (u16*)p;              p += (size_t)HIDDEN * EXPERTS * IN_DIM * 2;
    u16* wt1hi   = (u16*)p;              p += (size_t)HIDDEN * EXPERTS * INTER * 2;
    u16* wt1lo   = (u16*)p;              p += (size_t)HIDDEN * EXPERTS * INTER * 2;
    u16* wt2hi   = (u16*)p;              p += (size_t)64 * EXPERTS * INTER * 2;
    u16* wt2lo   = (u16*)p;              p += (size_t)64 * EXPERTS * INTER * 2;

    // 1) gate weight scaling + gate forward
    scale_rows_kernel<<<GATE_H, 64, 0, stream>>>(gw0, gc0, gW0s, IN_DIM);
    scale_rows_kernel<<<GATE_H, 64, 0, stream>>>(gw1, gc1, gW1s, GATE_H);
    scale_rows_kernel<<<EXPERTS, 64, 0, stream>>>(gw2, gc2, gW2s, GATE_H);
    gate_forward_kernel<<<BATCH, 128, 0, stream>>>(z, c, gW0s, gb0, gW1s, gb1,
                                                   gW2s, gb2, coeff);

    // 2) weight transpose + bf16 split
    wprep_kernel<IN_DIM, HIDDEN, HIDDEN><<<dim3(EXPERTS, IN_DIM / 64, HIDDEN / 64), 256, 0, stream>>>(w0, wt0hi, wt0lo);
    wprep_kernel<INTER,  HIDDEN, HIDDEN><<<dim3(EXPERTS, INTER / 64,  HIDDEN / 64), 256, 0, stream>>>(w1, wt1hi, wt1lo);
    wprep_kernel<INTER,  ACTIONS, 64><<<dim3(EXPERTS, INTER / 64, 1), 256, 0, stream>>>(w2, wt2hi, wt2lo);

    // 3) layers
    amat_kernel<IN_DIM, INPUT_SIZE><<<BATCH, 256, 0, stream>>>(z, c, xhi, xlo);
    moe_gemm<IN_DIM, HIDDEN, true><<<dim3(BATCH / 64, HIDDEN / 64), 256, 0, stream>>>(
        xhi, xlo, wt0hi, wt0lo, b0, coeff, H1);

    amat_kernel<INTER, HIDDEN><<<BATCH, 256, 0, stream>>>(z, H1, xhi, xlo);
    moe_gemm<INTER, HIDDEN, true><<<dim3(BATCH / 64, HIDDEN / 64), 256, 0, stream>>>(
        xhi, xlo, wt1hi, wt1lo, b1, coeff, H2);

    amat_kernel<INTER, HIDDEN><<<BATCH, 256, 0, stream>>>(z, H2, xhi, xlo);
    moe_gemm<INTER, ACTIONS, false><<<dim3(BATCH / 64, 1), 256, 0, stream>>>(
        xhi, xlo, wt2hi, wt2lo, b2, coeff, out);
}

// Round 3
// 344.513 us; speedup vs baseline: 3.0437x; 1.5086x over previous
//
#include <hip/hip_runtime.h>
#include <hip/hip_bf16.h>
#include <math.h>

#define BATCH 4096
#define INPUT_SIZE 256
#define LATENT 64
#define HIDDEN 512
#define ACTIONS 12
#define EXPERTS 8
#define GATE_H 128
#define IN_DIM (INPUT_SIZE + LATENT)   // 320
#define INTER (HIDDEN + LATENT)        // 576

typedef unsigned int u32;
typedef unsigned short u16;
typedef __attribute__((ext_vector_type(8))) short bf16x8;
typedef __attribute__((ext_vector_type(4))) float f32x4;
typedef __attribute__((ext_vector_type(16))) float f32x16;

__device__ __forceinline__ u16 f2bf(float x) {
    u32 u = __float_as_uint(x);
    u32 r = (u + 0x7fffu + ((u >> 16) & 1u)) >> 16;
    return (u16)r;
}
__device__ __forceinline__ float bf2f(u16 h) { return __uint_as_float(((u32)h) << 16); }

__device__ __forceinline__ void gload16(const void* g, void* lds) {
    __builtin_amdgcn_global_load_lds(
        (const __attribute__((address_space(1))) u32*)g,
        (__attribute__((address_space(3))) u32*)lds, 16, 0, 0);
}

// ---------------------------------------------------------------------------
// Gate: Lipschitz row scaling
// ---------------------------------------------------------------------------
__global__ void scale_rows_kernel(const float* __restrict__ W,
                                  const float* __restrict__ cc,
                                  float* __restrict__ Wout, int cols) {
    const int row = blockIdx.x;
    const float* w = W + (size_t)row * cols;
    float s = 0.f;
    for (int i = threadIdx.x; i < cols; i += 64) s += fabsf(w[i]);
    #pragma unroll
    for (int off = 32; off > 0; off >>= 1) s += __shfl_down(s, off, 64);
    s = __shfl(s, 0, 64);
    const float cv = cc[0];
    const float lipc = (cv > 0.f) ? (cv + log1pf(expf(-cv))) : log1pf(expf(cv));
    const float scale = fminf(lipc / s, 1.0f);
    float* o = Wout + (size_t)row * cols;
    for (int i = threadIdx.x; i < cols; i += 64) o[i] = w[i] * scale;
}

// ---------------------------------------------------------------------------
// Gate MLP -> softmax coeff
// ---------------------------------------------------------------------------
__global__ __launch_bounds__(128) void gate_forward_kernel(
    const float* __restrict__ z, const float* __restrict__ c,
    const float* __restrict__ W0, const float* __restrict__ b0,
    const float* __restrict__ W1, const float* __restrict__ b1,
    const float* __restrict__ W2, const float* __restrict__ b2,
    float* __restrict__ coeff) {
    __shared__ float x[IN_DIM];
    __shared__ float h[GATE_H];
    __shared__ float red[EXPERTS];

    const int b = blockIdx.x;
    const int t = threadIdx.x;

    if (t < LATENT) x[t] = z[(size_t)b * LATENT + t];
    for (int i = t; i < INPUT_SIZE; i += 128) x[LATENT + i] = c[(size_t)b * INPUT_SIZE + i];
    __syncthreads();
    {
        const float* w = W0 + (size_t)t * IN_DIM;
        float acc = b0[t];
        #pragma unroll 4
        for (int i = 0; i < IN_DIM; ++i) acc = fmaf(x[i], w[i], acc);
        float hv = acc > 0.f ? acc : expm1f(acc);
        __syncthreads();
        h[t] = hv;
        __syncthreads();
    }
    {
        const float* w = W1 + (size_t)t * GATE_H;
        float acc = b1[t];
        #pragma unroll 4
        for (int i = 0; i < GATE_H; ++i) acc = fmaf(h[i], w[i], acc);
        float hv = acc > 0.f ? acc : expm1f(acc);
        __syncthreads();
        h[t] = hv;
        __syncthreads();
    }
    if (t < EXPERTS) {
        const float* w = W2 + (size_t)t * GATE_H;
        float acc = b2[t];
        #pragma unroll 4
        for (int i = 0; i < GATE_H; ++i) acc = fmaf(h[i], w[i], acc);
        red[t] = acc;
    }
    __syncthreads();
    if (t == 0) {
        float m = red[0];
        #pragma unroll
        for (int i = 1; i < EXPERTS; ++i) m = fmaxf(m, red[i]);
        float e[EXPERTS];
        float s = 0.f;
        #pragma unroll
        for (int i = 0; i < EXPERTS; ++i) { e[i] = expf(red[i] - m); s += e[i]; }
        const float inv = 1.f / s;
        #pragma unroll
        for (int i = 0; i < EXPERTS; ++i) coeff[(size_t)b * EXPERTS + i] = e[i] * inv;
    }
}

// ---------------------------------------------------------------------------
// B prep: w (E, IN, OUT) f32 -> frag-packed bf16 planes [whi | whi | wlo]
// Bpk layout: [nblk][e][ksub][chunk 1KB], chunk: lane l holds
//   w[e][ksub*16 + (l>>5)*8 + i][nblk*32 + (l&31)]  (i = 0..7)
// ---------------------------------------------------------------------------
template<int IN, int OUT>
__global__ __launch_bounds__(256) void wprep_kernel(const float* __restrict__ w,
                                                    u16* __restrict__ Bpk) {
    constexpr int NK = IN / 16;
    __shared__ float tile[4][16][33];
    const int t = threadIdx.x, wv = t >> 6, l = t & 63;
    const int e = blockIdx.x, nblk = blockIdx.y, n0 = nblk * 32;
    const int col = l & 31, half = l >> 5;
    char* base = (char*)Bpk + ((size_t)(nblk * EXPERTS + e) * 3 * NK) * 1024;

    for (int jj = wv; jj < NK; jj += 4) {
        #pragma unroll
        for (int i = 0; i < 8; ++i) {
            const int r = i * 2 + half;
            float v = 0.f;
            if (n0 + col < OUT) v = w[((size_t)e * IN + jj * 16 + r) * OUT + n0 + col];
            tile[wv][r][col] = v;
        }
        bf16x8 hh, ll;
        #pragma unroll
        for (int i = 0; i < 8; ++i) {
            const float v = tile[wv][half * 8 + i][col];
            const u16 hb = f2bf(v);
            hh[i] = (short)hb;
            ll[i] = (short)f2bf(v - bf2f(hb));
        }
        *(bf16x8*)(base + (size_t)jj * 1024 + l * 16) = hh;
        *(bf16x8*)(base + (size_t)(NK + jj) * 1024 + l * 16) = hh;
        *(bf16x8*)(base + (size_t)(2 * NK + jj) * 1024 + l * 16) = ll;
    }
}

// ---------------------------------------------------------------------------
// A prep layer0: [z|c] -> frag-packed planes [xhi | xlo | xhi], NK=20
// Apk layout: [bblk][ksub][chunk 1KB], chunk: lane l holds
//   x[bblk*32 + (l&31)][ksub*16 + (l>>5)*8 + i]
// ---------------------------------------------------------------------------
__global__ __launch_bounds__(256) void amat0_kernel(const float* __restrict__ z,
                                                    const float* __restrict__ c,
                                                    u16* __restrict__ Apk) {
    constexpr int NK = 20;
    const int t = threadIdx.x, wv = t >> 6, l = t & 63;
    const int bblk = blockIdx.x;
    const int r = l & 31, half = l >> 5;
    const int row = bblk * 32 + r;
    char* base = (char*)Apk + (size_t)bblk * (3 * NK) * 1024;

    for (int jj = wv; jj < NK; jj += 4) {
        const int k = jj * 16 + half * 8;
        const float* src = (k < LATENT) ? (z + (size_t)row * LATENT + k)
                                        : (c + (size_t)row * INPUT_SIZE + (k - LATENT));
        bf16x8 hh, ll;
        #pragma unroll
        for (int i = 0; i < 8; ++i) {
            const float v = src[i];
            const u16 hb = f2bf(v);
            hh[i] = (short)hb;
            ll[i] = (short)f2bf(v - bf2f(hb));
        }
        *(bf16x8*)(base + (size_t)jj * 1024 + l * 16) = hh;
        *(bf16x8*)(base + (size_t)(NK + jj) * 1024 + l * 16) = ll;
        *(bf16x8*)(base + (size_t)(2 * NK + jj) * 1024 + l * 16) = hh;
    }
}

// ---------------------------------------------------------------------------
// z part of Apk1/Apk2 (IN=576, NK=36): ksubs 0..3 (hi), 36..39 (lo), 72..75 (hi)
// ---------------------------------------------------------------------------
__global__ __launch_bounds__(256) void zpack_kernel(const float* __restrict__ z,
                                                    u16* __restrict__ Apk1,
                                                    u16* __restrict__ Apk2) {
    constexpr int NK = 36;
    const int t = threadIdx.x, wv = t >> 6, l = t & 63;
    const int bblk = blockIdx.x;
    const int r = l & 31, half = l >> 5;
    const int row = bblk * 32 + r;
    const int jj = wv;  // 0..3
    const int k = jj * 16 + half * 8;
    const float* src = z + (size_t)row * LATENT + k;
    bf16x8 hh, ll;
    #pragma unroll
    for (int i = 0; i < 8; ++i) {
        const float v = src[i];
        const u16 hb = f2bf(v);
        hh[i] = (short)hb;
        ll[i] = (short)f2bf(v - bf2f(hb));
    }
    const size_t o0 = (size_t)bblk * (3 * NK) * 1024 + l * 16;
    *(bf16x8*)((char*)Apk1 + o0 + (size_t)jj * 1024) = hh;
    *(bf16x8*)((char*)Apk1 + o0 + (size_t)(NK + jj) * 1024) = ll;
    *(bf16x8*)((char*)Apk1 + o0 + (size_t)(2 * NK + jj) * 1024) = hh;
    *(bf16x8*)((char*)Apk2 + o0 + (size_t)jj * 1024) = hh;
    *(bf16x8*)((char*)Apk2 + o0 + (size_t)(NK + jj) * 1024) = ll;
    *(bf16x8*)((char*)Apk2 + o0 + (size_t)(2 * NK + jj) * 1024) = hh;
}

// ---------------------------------------------------------------------------
// Reduce split-K partials + coeff-mixed bias + ELU, emit packed A for next
// layer (h occupies k=64..576 -> ksubs 4..35 of each plane).
// ---------------------------------------------------------------------------
template<int NPART>
__global__ __launch_bounds__(256) void reduce_pack_kernel(
    const float* __restrict__ P, const float* __restrict__ coeff,
    const float* __restrict__ bias, u16* __restrict__ ApkNext) {
    constexpr int NK = 36;
    __shared__ float biasS[EXPERTS][HIDDEN];
    __shared__ float coeffS[32][9];
    const int t = threadIdx.x, wv = t >> 6, l = t & 63;
    const int bblk = blockIdx.x;
    const int r = l & 31, half = l >> 5;
    const int row = bblk * 32 + r;

    for (int idx = t; idx < EXPERTS * HIDDEN; idx += 256)
        biasS[idx >> 9][idx & 511] = bias[idx];
    for (int idx = t; idx < 32 * 8; idx += 256)
        coeffS[idx >> 3][idx & 7] = coeff[(size_t)(bblk * 32 + (idx >> 3)) * 8 + (idx & 7)];
    __syncthreads();

    char* base = (char*)ApkNext + (size_t)bblk * (3 * NK) * 1024;
    for (int jj = wv; jj < 32; jj += 4) {
        const int cb = jj * 16 + half * 8;
        float v[8];
        #pragma unroll
        for (int i = 0; i < 8; ++i) v[i] = 0.f;
        #pragma unroll
        for (int p = 0; p < NPART; ++p) {
            const float4* q = (const float4*)(P + ((size_t)p * BATCH + row) * HIDDEN + cb);
            const float4 a = q[0], b = q[1];
            v[0] += a.x; v[1] += a.y; v[2] += a.z; v[3] += a.w;
            v[4] += b.x; v[5] += b.y; v[6] += b.z; v[7] += b.w;
        }
        #pragma unroll
        for (int e = 0; e < EXPERTS; ++e) {
            const float cv = coeffS[r][e];
            #pragma unroll
            for (int i = 0; i < 8; ++i) v[i] = fmaf(cv, biasS[e][cb + i], v[i]);
        }
        bf16x8 hh, ll;
        #pragma unroll
        for (int i = 0; i < 8; ++i) {
            const float hv = v[i] > 0.f ? v[i] : expm1f(v[i]);
            const u16 hb = f2bf(hv);
            hh[i] = (short)hb;
            ll[i] = (short)f2bf(hv - bf2f(hb));
        }
        *(bf16x8*)(base + (size_t)(4 + jj) * 1024 + l * 16) = hh;
        *(bf16x8*)(base + (size_t)(NK + 4 + jj) * 1024 + l * 16) = ll;
        *(bf16x8*)(base + (size_t)(2 * NK + 4 + jj) * 1024 + l * 16) = hh;
    }
}

// ---------------------------------------------------------------------------
// Final reduce: 8 partials + coeff-mixed bias, no activation, OUT=12
// ---------------------------------------------------------------------------
__global__ __launch_bounds__(256) void reduce_out_kernel(
    const float* __restrict__ P2, const float* __restrict__ coeff,
    const float* __restrict__ b2, float* __restrict__ out) {
    const int t = threadIdx.x;
    const int bblk = blockIdx.x;
    for (int idx = t; idx < 32 * ACTIONS; idx += 256) {
        const int r = idx / ACTIONS, n = idx % ACTIONS;
        const int row = bblk * 32 + r;
        float s = 0.f;
        #pragma unroll
        for (int p = 0; p < 8; ++p) s += P2[((size_t)p * BATCH + row) * 32 + n];
        const float* cf = coeff + (size_t)row * 8;
        #pragma unroll
        for (int e = 0; e < 8; ++e) s = fmaf(cf[e], b2[e * ACTIONS + n], s);
        out[(size_t)row * ACTIONS + n] = s;
    }
}

// ---------------------------------------------------------------------------
// MoE GEMM: frag-packed A (LDS dbuf, gload_lds) x frag-packed B (reg prefetch)
// Block tile 128 x (32*WN), waves 2 x WN (wave tile 64x32), 32x32x16 bf16 MFMA.
// e-inner (EPB experts per block), A-frags hoisted to regs once per K-step.
// grid.z = split-K part. P = f32 partials [part][B][OUTW].
// ---------------------------------------------------------------------------
template<int NK, int WN, int EPB, int OUTW>
__global__ __launch_bounds__(128 * WN) void moe_gemm(
    const u16* __restrict__ Apk, const u16* __restrict__ Bpk,
    const float* __restrict__ coeff, float* __restrict__ P) {
    constexpr int NST = (3 * NK) / 4;     // K-steps of 64
    constexpr int NWAVE = 2 * WN;
    constexpr int CPW = 16 / NWAVE;       // staged 1KB chunks per wave per step

    __shared__ __align__(16) char As[32768];
    __shared__ float coeffT[EPB][128];

    const int t = threadIdx.x, wv = t >> 6, l = t & 63;
    const int wr = wv & 1, wc = wv >> 1;
    const int b0 = blockIdx.x * 128;
    const int bblk0 = blockIdx.x * 4;
    const int nblkg = blockIdx.y * WN + wc;
    const int part = blockIdx.z;
    const int estart = part * EPB;

    for (int idx = t; idx < EPB * 128; idx += 128 * WN)
        coeffT[idx >> 7][idx & 127] =
            coeff[(size_t)(b0 + (idx & 127)) * EXPERTS + estart + (idx >> 7)];

    const char* Ab = (const char*)Apk;
    const char* Bbase[EPB];
    #pragma unroll
    for (int e = 0; e < EPB; ++e)
        Bbase[e] = (const char*)Bpk +
                   ((size_t)(nblkg * EXPERTS + estart + e) * 3 * NK) * 1024 + l * 16;

    f32x16 accE[EPB][2];
    #pragma unroll
    for (int e = 0; e < EPB; ++e) { accE[e][0] = (f32x16)0.f; accE[e][1] = (f32x16)0.f; }

    bf16x8 breg0[EPB][4], breg1[EPB][4];

    // prologue: stage step 0 (buf0) + B step 0
    #pragma unroll
    for (int q = 0; q < CPW; ++q) {
        const int cf = wv * CPW + q, bb = cf >> 2, kq = cf & 3;
        gload16(Ab + ((size_t)(bblk0 + bb) * (3 * NK) + kq) * 1024 + l * 16,
                As + cf * 1024 + l * 16);
    }
    #pragma unroll
    for (int e = 0; e < EPB; ++e)
        #pragma unroll
        for (int q = 0; q < 4; ++q)
            breg0[e][q] = *(const bf16x8*)(Bbase[e] + q * 1024);
    __syncthreads();

#define GSTEP(CUR, NXT, KS) {                                                     \
    if ((KS) + 1 < NST) {                                                         \
        _Pragma("unroll")                                                         \
        for (int q = 0; q < CPW; ++q) {                                           \
            const int cf = wv * CPW + q, bb = cf >> 2, kq = cf & 3;               \
            gload16(Ab + ((size_t)(bblk0 + bb) * (3 * NK) + ((KS) + 1) * 4 + kq) * 1024 + l * 16, \
                    As + (NXT) * 16384 + cf * 1024 + l * 16);                     \
        }                                                                         \
        _Pragma("unroll")                                                         \
        for (int e = 0; e < EPB; ++e) {                                           \
            _Pragma("unroll")                                                     \
            for (int q = 0; q < 4; ++q)                                           \
                breg##NXT[e][q] = *(const bf16x8*)(Bbase[e] + (size_t)((KS) + 1) * 4096 + q * 1024); \
        }                                                                         \
    }                                                                             \
    bf16x8 af0[4], af1[4];                                                        \
    _Pragma("unroll")                                                             \
    for (int j = 0; j < 4; ++j) {                                                 \
        af0[j] = *(const bf16x8*)(As + (CUR) * 16384 + ((wr * 2 + 0) * 4 + j) * 1024 + l * 16); \
        af1[j] = *(const bf16x8*)(As + (CUR) * 16384 + ((wr * 2 + 1) * 4 + j) * 1024 + l * 16); \
    }                                                                             \
    _Pragma("unroll")                                                             \
    for (int e = 0; e < EPB; ++e) {                                               \
        _Pragma("unroll")                                                         \
        for (int j = 0; j < 4; ++j) {                                             \
            accE[e][0] = __builtin_amdgcn_mfma_f32_32x32x16_bf16(af0[j], breg##CUR[e][j], accE[e][0], 0, 0, 0); \
            accE[e][1] = __builtin_amdgcn_mfma_f32_32x32x16_bf16(af1[j], breg##CUR[e][j], accE[e][1], 0, 0, 0); \
        }                                                                         \
    }                                                                             \
    __syncthreads(); }

    #pragma unroll 1
    for (int ks = 0; ks < NST - 1; ks += 2) {
        GSTEP(0, 1, ks)
        GSTEP(1, 0, ks + 1)
    }
    GSTEP(0, 1, NST - 1)
#undef GSTEP

    // epilogue: coeff fold + partial store
    const int ncol = nblkg * 32 + (l & 31);
    #pragma unroll
    for (int m = 0; m < 2; ++m) {
        #pragma unroll
        for (int g = 0; g < 16; ++g) {
            const int rloc = (g & 3) + 8 * (g >> 2) + 4 * (l >> 5);
            const int row = wr * 64 + m * 32 + rloc;
            float v = 0.f;
            #pragma unroll
            for (int e = 0; e < EPB; ++e) v = fmaf(coeffT[e][row], accE[e][m][g], v);
            P[((size_t)part * BATCH + b0 + row) * OUTW + ncol] = v;
        }
    }
}

// ---------------------------------------------------------------------------
extern "C" void kernel_launch(void* const* d_in, const int* in_sizes, int n_in,
                              void* d_out, int out_size, void* d_ws, size_t ws_size,
                              hipStream_t stream) {
    const float* z   = (const float*)d_in[0];
    const float* c   = (const float*)d_in[1];
    const float* w0  = (const float*)d_in[2];
    const float* b0  = (const float*)d_in[3];
    const float* w1  = (const float*)d_in[4];
    const float* b1  = (const float*)d_in[5];
    const float* w2  = (const float*)d_in[6];
    const float* b2  = (const float*)d_in[7];
    const float* gw0 = (const float*)d_in[8];
    const float* gb0 = (const float*)d_in[9];
    const float* gc0 = (const float*)d_in[10];
    const float* gw1 = (const float*)d_in[11];
    const float* gb1 = (const float*)d_in[12];
    const float* gc1 = (const float*)d_in[13];
    const float* gw2 = (const float*)d_in[14];
    const float* gb2 = (const float*)d_in[15];
    const float* gc2 = (const float*)d_in[16];
    float* out = (float*)d_out;

    // workspace layout (all chunk-aligned)
    char* p = (char*)d_ws;
    float* coeff = (float*)p;  p += (size_t)BATCH * EXPERTS * 4;          // 128K
    float* gW0s  = (float*)p;  p += (size_t)GATE_H * IN_DIM * 4;
    float* gW1s  = (float*)p;  p += (size_t)GATE_H * GATE_H * 4;
    float* gW2s  = (float*)p;  p += (size_t)EXPERTS * GATE_H * 4;
    u16* Apk0 = (u16*)p;       p += (size_t)128 * 60 * 1024;              // 7.5 MB
    u16* Apk1 = (u16*)p;       p += (size_t)128 * 108 * 1024;             // 13.5 MB
    u16* Apk2 = (u16*)p;       p += (size_t)128 * 108 * 1024;
    u16* Bpk0 = (u16*)p;       p += (size_t)16 * 8 * 60 * 1024;           // 7.5 MB
    u16* Bpk1 = (u16*)p;       p += (size_t)16 * 8 * 108 * 1024;          // 13.5 MB
    u16* Bpk2 = (u16*)p;       p += (size_t)1 * 8 * 108 * 1024;           // 0.86 MB
    float* P  = (float*)p;     p += (size_t)4 * BATCH * HIDDEN * 4;       // 32 MB

    // gate
    scale_rows_kernel<<<GATE_H, 64, 0, stream>>>(gw0, gc0, gW0s, IN_DIM);
    scale_rows_kernel<<<GATE_H, 64, 0, stream>>>(gw1, gc1, gW1s, GATE_H);
    scale_rows_kernel<<<EXPERTS, 64, 0, stream>>>(gw2, gc2, gW2s, GATE_H);
    gate_forward_kernel<<<BATCH, 128, 0, stream>>>(z, c, gW0s, gb0, gW1s, gb1,
                                                   gW2s, gb2, coeff);

    // weight packing
    wprep_kernel<IN_DIM, HIDDEN><<<dim3(EXPERTS, 16), 256, 0, stream>>>(w0, Bpk0);
    wprep_kernel<INTER,  HIDDEN><<<dim3(EXPERTS, 16), 256, 0, stream>>>(w1, Bpk1);
    wprep_kernel<INTER, ACTIONS><<<dim3(EXPERTS, 1), 256, 0, stream>>>(w2, Bpk2);

    // activation packing for layer 0 + z-regions of layer1/2
    amat0_kernel<<<128, 256, 0, stream>>>(z, c, Apk0);
    zpack_kernel<<<128, 256, 0, stream>>>(z, Apk1, Apk2);

    // layer 0: IN=320 (NK=20), split-K 4 x 2 experts
    moe_gemm<20, 2, 2, HIDDEN><<<dim3(32, 8, 4), 256, 0, stream>>>(Apk0, Bpk0, coeff, P);
    reduce_pack_kernel<4><<<128, 256, 0, stream>>>(P, coeff, b0, Apk1);

    // layer 1: IN=576 (NK=36)
    moe_gemm<36, 2, 2, HIDDEN><<<dim3(32, 8, 4), 256, 0, stream>>>(Apk1, Bpk1, coeff, P);
    reduce_pack_kernel<4><<<128, 256, 0, stream>>>(P, coeff, b1, Apk2);

    // layer 2: IN=576, OUT=12 (padded 32), split-K 8 x 1 expert
    moe_gemm<36, 1, 1, 32><<<dim3(32, 1, 8), 128, 0, stream>>>(Apk2, Bpk2, coeff, P);
    reduce_out_kernel<<<128, 256, 0, stream>>>(P, coeff, b2, out);
}

// Round 4
// 270.089 us; speedup vs baseline: 3.8825x; 1.2756x over previous
//
#include <hip/hip_runtime.h>
#include <hip/hip_bf16.h>
#include <math.h>

#define BATCH 4096
#define INPUT_SIZE 256
#define LATENT 64
#define HIDDEN 512
#define ACTIONS 12
#define EXPERTS 8
#define GATE_H 128
#define IN_DIM (INPUT_SIZE + LATENT)   // 320
#define INTER (HIDDEN + LATENT)        // 576

typedef unsigned int u32;
typedef unsigned short u16;
typedef __attribute__((ext_vector_type(8))) short bf16x8;
typedef __attribute__((ext_vector_type(4))) float f32x4;
typedef __attribute__((ext_vector_type(16))) float f32x16;

__device__ __forceinline__ u16 f2bf(float x) {
    u32 u = __float_as_uint(x);
    u32 r = (u + 0x7fffu + ((u >> 16) & 1u)) >> 16;
    return (u16)r;
}
__device__ __forceinline__ float bf2f(u16 h) { return __uint_as_float(((u32)h) << 16); }

__device__ __forceinline__ void gload16(const void* g, void* lds) {
    __builtin_amdgcn_global_load_lds(
        (const __attribute__((address_space(1))) u32*)g,
        (__attribute__((address_space(3))) u32*)lds, 16, 0, 0);
}

// ---------------------------------------------------------------------------
// Gate: Lipschitz row scaling, writing the TRANSPOSED scaled matrix
// Wt[i][row] = W[row][i] * min(softplus(c)/rowL1, 1)
// ---------------------------------------------------------------------------
__global__ void scale_rows_t_kernel(const float* __restrict__ W,
                                    const float* __restrict__ cc,
                                    float* __restrict__ Wt, int cols, int rows) {
    const int row = blockIdx.x;
    const float* w = W + (size_t)row * cols;
    float s = 0.f;
    for (int i = threadIdx.x; i < cols; i += 64) s += fabsf(w[i]);
    #pragma unroll
    for (int off = 32; off > 0; off >>= 1) s += __shfl_down(s, off, 64);
    s = __shfl(s, 0, 64);
    const float cv = cc[0];
    const float lipc = (cv > 0.f) ? (cv + log1pf(expf(-cv))) : log1pf(expf(cv));
    const float scale = fminf(lipc / s, 1.0f);
    for (int i = threadIdx.x; i < cols; i += 64)
        Wt[(size_t)i * rows + row] = w[i] * scale;
}

// ---------------------------------------------------------------------------
// Gate MLP v2: 4 samples/block, 128 threads (thread = neuron), transposed
// weights (coalesced loads), x/h staged in padded LDS.
// ---------------------------------------------------------------------------
#define GS 4
__global__ __launch_bounds__(128) void gate_forward_v2(
    const float* __restrict__ z, const float* __restrict__ c,
    const float* __restrict__ W0t, const float* __restrict__ b0,
    const float* __restrict__ W1t, const float* __restrict__ b1,
    const float* __restrict__ W2t, const float* __restrict__ b2,
    float* __restrict__ coeff) {
    __shared__ float xs[GS][IN_DIM + 1];
    __shared__ float h1s[GS][GATE_H + 1];
    __shared__ float h2s[GS][GATE_H + 1];
    __shared__ float red[GS][EXPERTS];

    const int b4 = blockIdx.x * GS;
    const int t = threadIdx.x;

    for (int idx = t; idx < GS * IN_DIM; idx += 128) {
        const int s = idx / IN_DIM, i = idx - s * IN_DIM;
        xs[s][i] = (i < LATENT) ? z[(size_t)(b4 + s) * LATENT + i]
                                : c[(size_t)(b4 + s) * INPUT_SIZE + (i - LATENT)];
    }
    __syncthreads();

    // layer 0: 320 -> 128
    {
        float acc[GS];
        #pragma unroll
        for (int s = 0; s < GS; ++s) acc[s] = b0[t];
        #pragma unroll 4
        for (int i = 0; i < IN_DIM; ++i) {
            const float wv = W0t[(size_t)i * GATE_H + t];
            #pragma unroll
            for (int s = 0; s < GS; ++s) acc[s] = fmaf(xs[s][i], wv, acc[s]);
        }
        #pragma unroll
        for (int s = 0; s < GS; ++s)
            h1s[s][t] = acc[s] > 0.f ? acc[s] : expm1f(acc[s]);
    }
    __syncthreads();

    // layer 1: 128 -> 128
    {
        float acc[GS];
        #pragma unroll
        for (int s = 0; s < GS; ++s) acc[s] = b1[t];
        #pragma unroll 4
        for (int i = 0; i < GATE_H; ++i) {
            const float wv = W1t[(size_t)i * GATE_H + t];
            #pragma unroll
            for (int s = 0; s < GS; ++s) acc[s] = fmaf(h1s[s][i], wv, acc[s]);
        }
        #pragma unroll
        for (int s = 0; s < GS; ++s)
            h2s[s][t] = acc[s] > 0.f ? acc[s] : expm1f(acc[s]);
    }
    __syncthreads();

    // layer 2: 128 -> 8 (32 threads: (s,e) pairs)
    if (t < GS * EXPERTS) {
        const int s = t >> 3, e = t & 7;
        float acc = b2[e];
        #pragma unroll 4
        for (int i = 0; i < GATE_H; ++i)
            acc = fmaf(h2s[s][i], W2t[(size_t)i * EXPERTS + e], acc);
        red[s][e] = acc;
    }
    __syncthreads();

    if (t < GS) {
        float m = red[t][0];
        #pragma unroll
        for (int i = 1; i < EXPERTS; ++i) m = fmaxf(m, red[t][i]);
        float e[EXPERTS];
        float sum = 0.f;
        #pragma unroll
        for (int i = 0; i < EXPERTS; ++i) { e[i] = expf(red[t][i] - m); sum += e[i]; }
        const float inv = 1.f / sum;
        #pragma unroll
        for (int i = 0; i < EXPERTS; ++i)
            coeff[(size_t)(b4 + t) * EXPERTS + i] = e[i] * inv;
    }
}

// ---------------------------------------------------------------------------
// B prep: w (E, IN, OUT) f32 -> frag-packed bf16 planes [whi | whi | wlo]
// ---------------------------------------------------------------------------
template<int IN, int OUT>
__global__ __launch_bounds__(256) void wprep_kernel(const float* __restrict__ w,
                                                    u16* __restrict__ Bpk) {
    constexpr int NK = IN / 16;
    __shared__ float tile[4][16][33];
    const int t = threadIdx.x, wv = t >> 6, l = t & 63;
    const int e = blockIdx.x, nblk = blockIdx.y, n0 = nblk * 32;
    const int col = l & 31, half = l >> 5;
    char* base = (char*)Bpk + ((size_t)(nblk * EXPERTS + e) * 3 * NK) * 1024;

    for (int jj = wv; jj < NK; jj += 4) {
        #pragma unroll
        for (int i = 0; i < 8; ++i) {
            const int r = i * 2 + half;
            float v = 0.f;
            if (n0 + col < OUT) v = w[((size_t)e * IN + jj * 16 + r) * OUT + n0 + col];
            tile[wv][r][col] = v;
        }
        bf16x8 hh, ll;
        #pragma unroll
        for (int i = 0; i < 8; ++i) {
            const float v = tile[wv][half * 8 + i][col];
            const u16 hb = f2bf(v);
            hh[i] = (short)hb;
            ll[i] = (short)f2bf(v - bf2f(hb));
        }
        *(bf16x8*)(base + (size_t)jj * 1024 + l * 16) = hh;
        *(bf16x8*)(base + (size_t)(NK + jj) * 1024 + l * 16) = hh;
        *(bf16x8*)(base + (size_t)(2 * NK + jj) * 1024 + l * 16) = ll;
    }
}

// ---------------------------------------------------------------------------
// A prep layer0: [z|c] -> frag-packed planes [xhi | xlo | xhi], NK=20
// ---------------------------------------------------------------------------
__global__ __launch_bounds__(256) void amat0_kernel(const float* __restrict__ z,
                                                    const float* __restrict__ c,
                                                    u16* __restrict__ Apk) {
    constexpr int NK = 20;
    const int t = threadIdx.x, wv = t >> 6, l = t & 63;
    const int bblk = blockIdx.x;
    const int r = l & 31, half = l >> 5;
    const int row = bblk * 32 + r;
    char* base = (char*)Apk + (size_t)bblk * (3 * NK) * 1024;

    for (int jj = wv; jj < NK; jj += 4) {
        const int k = jj * 16 + half * 8;
        const float* src = (k < LATENT) ? (z + (size_t)row * LATENT + k)
                                        : (c + (size_t)row * INPUT_SIZE + (k - LATENT));
        bf16x8 hh, ll;
        #pragma unroll
        for (int i = 0; i < 8; ++i) {
            const float v = src[i];
            const u16 hb = f2bf(v);
            hh[i] = (short)hb;
            ll[i] = (short)f2bf(v - bf2f(hb));
        }
        *(bf16x8*)(base + (size_t)jj * 1024 + l * 16) = hh;
        *(bf16x8*)(base + (size_t)(NK + jj) * 1024 + l * 16) = ll;
        *(bf16x8*)(base + (size_t)(2 * NK + jj) * 1024 + l * 16) = hh;
    }
}

// ---------------------------------------------------------------------------
// z part of Apk1/Apk2 (IN=576, NK=36)
// ---------------------------------------------------------------------------
__global__ __launch_bounds__(256) void zpack_kernel(const float* __restrict__ z,
                                                    u16* __restrict__ Apk1,
                                                    u16* __restrict__ Apk2) {
    constexpr int NK = 36;
    const int t = threadIdx.x, wv = t >> 6, l = t & 63;
    const int bblk = blockIdx.x;
    const int r = l & 31, half = l >> 5;
    const int row = bblk * 32 + r;
    const int jj = wv;  // 0..3
    const int k = jj * 16 + half * 8;
    const float* src = z + (size_t)row * LATENT + k;
    bf16x8 hh, ll;
    #pragma unroll
    for (int i = 0; i < 8; ++i) {
        const float v = src[i];
        const u16 hb = f2bf(v);
        hh[i] = (short)hb;
        ll[i] = (short)f2bf(v - bf2f(hb));
    }
    const size_t o0 = (size_t)bblk * (3 * NK) * 1024 + l * 16;
    *(bf16x8*)((char*)Apk1 + o0 + (size_t)jj * 1024) = hh;
    *(bf16x8*)((char*)Apk1 + o0 + (size_t)(NK + jj) * 1024) = ll;
    *(bf16x8*)((char*)Apk1 + o0 + (size_t)(2 * NK + jj) * 1024) = hh;
    *(bf16x8*)((char*)Apk2 + o0 + (size_t)jj * 1024) = hh;
    *(bf16x8*)((char*)Apk2 + o0 + (size_t)(NK + jj) * 1024) = ll;
    *(bf16x8*)((char*)Apk2 + o0 + (size_t)(2 * NK + jj) * 1024) = hh;
}

// ---------------------------------------------------------------------------
// Reduce split-K partials + coeff-mixed bias + ELU, emit packed A for next layer
// ---------------------------------------------------------------------------
template<int NPART>
__global__ __launch_bounds__(256) void reduce_pack_kernel(
    const float* __restrict__ P, const float* __restrict__ coeff,
    const float* __restrict__ bias, u16* __restrict__ ApkNext) {
    constexpr int NK = 36;
    __shared__ float biasS[EXPERTS][HIDDEN];
    __shared__ float coeffS[32][9];
    const int t = threadIdx.x, wv = t >> 6, l = t & 63;
    const int bblk = blockIdx.x;
    const int r = l & 31, half = l >> 5;
    const int row = bblk * 32 + r;

    for (int idx = t; idx < EXPERTS * HIDDEN; idx += 256)
        biasS[idx >> 9][idx & 511] = bias[idx];
    for (int idx = t; idx < 32 * 8; idx += 256)
        coeffS[idx >> 3][idx & 7] = coeff[(size_t)(bblk * 32 + (idx >> 3)) * 8 + (idx & 7)];
    __syncthreads();

    char* base = (char*)ApkNext + (size_t)bblk * (3 * NK) * 1024;
    for (int jj = wv; jj < 32; jj += 4) {
        const int cb = jj * 16 + half * 8;
        float v[8];
        #pragma unroll
        for (int i = 0; i < 8; ++i) v[i] = 0.f;
        #pragma unroll
        for (int p = 0; p < NPART; ++p) {
            const float4* q = (const float4*)(P + ((size_t)p * BATCH + row) * HIDDEN + cb);
            const float4 a = q[0], b = q[1];
            v[0] += a.x; v[1] += a.y; v[2] += a.z; v[3] += a.w;
            v[4] += b.x; v[5] += b.y; v[6] += b.z; v[7] += b.w;
        }
        #pragma unroll
        for (int e = 0; e < EXPERTS; ++e) {
            const float cv = coeffS[r][e];
            #pragma unroll
            for (int i = 0; i < 8; ++i) v[i] = fmaf(cv, biasS[e][cb + i], v[i]);
        }
        bf16x8 hh, ll;
        #pragma unroll
        for (int i = 0; i < 8; ++i) {
            const float hv = v[i] > 0.f ? v[i] : expm1f(v[i]);
            const u16 hb = f2bf(hv);
            hh[i] = (short)hb;
            ll[i] = (short)f2bf(hv - bf2f(hb));
        }
        *(bf16x8*)(base + (size_t)(4 + jj) * 1024 + l * 16) = hh;
        *(bf16x8*)(base + (size_t)(NK + 4 + jj) * 1024 + l * 16) = ll;
        *(bf16x8*)(base + (size_t)(2 * NK + 4 + jj) * 1024 + l * 16) = hh;
    }
}

// ---------------------------------------------------------------------------
// Final reduce: 8 partials + coeff-mixed bias, no activation, OUT=12
// ---------------------------------------------------------------------------
__global__ __launch_bounds__(256) void reduce_out_kernel(
    const float* __restrict__ P2, const float* __restrict__ coeff,
    const float* __restrict__ b2, float* __restrict__ out) {
    const int t = threadIdx.x;
    const int bblk = blockIdx.x;
    for (int idx = t; idx < 32 * ACTIONS; idx += 256) {
        const int r = idx / ACTIONS, n = idx % ACTIONS;
        const int row = bblk * 32 + r;
        float s = 0.f;
        #pragma unroll
        for (int p = 0; p < 8; ++p) s += P2[((size_t)p * BATCH + row) * 32 + n];
        const float* cf = coeff + (size_t)row * 8;
        #pragma unroll
        for (int e = 0; e < 8; ++e) s = fmaf(cf[e], b2[e * ACTIONS + n], s);
        out[(size_t)row * ACTIONS + n] = s;
    }
}

// ---------------------------------------------------------------------------
// MoE GEMM (unchanged from round 2 — verified)
// ---------------------------------------------------------------------------
template<int NK, int WN, int EPB, int OUTW>
__global__ __launch_bounds__(128 * WN) void moe_gemm(
    const u16* __restrict__ Apk, const u16* __restrict__ Bpk,
    const float* __restrict__ coeff, float* __restrict__ P) {
    constexpr int NST = (3 * NK) / 4;
    constexpr int NWAVE = 2 * WN;
    constexpr int CPW = 16 / NWAVE;

    __shared__ __align__(16) char As[32768];
    __shared__ float coeffT[EPB][128];

    const int t = threadIdx.x, wv = t >> 6, l = t & 63;
    const int wr = wv & 1, wc = wv >> 1;
    const int b0 = blockIdx.x * 128;
    const int bblk0 = blockIdx.x * 4;
    const int nblkg = blockIdx.y * WN + wc;
    const int part = blockIdx.z;
    const int estart = part * EPB;

    for (int idx = t; idx < EPB * 128; idx += 128 * WN)
        coeffT[idx >> 7][idx & 127] =
            coeff[(size_t)(b0 + (idx & 127)) * EXPERTS + estart + (idx >> 7)];

    const char* Ab = (const char*)Apk;
    const char* Bbase[EPB];
    #pragma unroll
    for (int e = 0; e < EPB; ++e)
        Bbase[e] = (const char*)Bpk +
                   ((size_t)(nblkg * EXPERTS + estart + e) * 3 * NK) * 1024 + l * 16;

    f32x16 accE[EPB][2];
    #pragma unroll
    for (int e = 0; e < EPB; ++e) { accE[e][0] = (f32x16)0.f; accE[e][1] = (f32x16)0.f; }

    bf16x8 breg0[EPB][4], breg1[EPB][4];

    #pragma unroll
    for (int q = 0; q < CPW; ++q) {
        const int cf = wv * CPW + q, bb = cf >> 2, kq = cf & 3;
        gload16(Ab + ((size_t)(bblk0 + bb) * (3 * NK) + kq) * 1024 + l * 16,
                As + cf * 1024 + l * 16);
    }
    #pragma unroll
    for (int e = 0; e < EPB; ++e)
        #pragma unroll
        for (int q = 0; q < 4; ++q)
            breg0[e][q] = *(const bf16x8*)(Bbase[e] + q * 1024);
    __syncthreads();

#define GSTEP(CUR, NXT, KS) {                                                     \
    if ((KS) + 1 < NST) {                                                         \
        _Pragma("unroll")                                                         \
        for (int q = 0; q < CPW; ++q) {                                           \
            const int cf = wv * CPW + q, bb = cf >> 2, kq = cf & 3;               \
            gload16(Ab + ((size_t)(bblk0 + bb) * (3 * NK) + ((KS) + 1) * 4 + kq) * 1024 + l * 16, \
                    As + (NXT) * 16384 + cf * 1024 + l * 16);                     \
        }                                                                         \
        _Pragma("unroll")                                                         \
        for (int e = 0; e < EPB; ++e) {                                           \
            _Pragma("unroll")                                                     \
            for (int q = 0; q < 4; ++q)                                           \
                breg##NXT[e][q] = *(const bf16x8*)(Bbase[e] + (size_t)((KS) + 1) * 4096 + q * 1024); \
        }                                                                         \
    }                                                                             \
    bf16x8 af0[4], af1[4];                                                        \
    _Pragma("unroll")                                                             \
    for (int j = 0; j < 4; ++j) {                                                 \
        af0[j] = *(const bf16x8*)(As + (CUR) * 16384 + ((wr * 2 + 0) * 4 + j) * 1024 + l * 16); \
        af1[j] = *(const bf16x8*)(As + (CUR) * 16384 + ((wr * 2 + 1) * 4 + j) * 1024 + l * 16); \
    }                                                                             \
    _Pragma("unroll")                                                             \
    for (int e = 0; e < EPB; ++e) {                                               \
        _Pragma("unroll")                                                         \
        for (int j = 0; j < 4; ++j) {                                             \
            accE[e][0] = __builtin_amdgcn_mfma_f32_32x32x16_bf16(af0[j], breg##CUR[e][j], accE[e][0], 0, 0, 0); \
            accE[e][1] = __builtin_amdgcn_mfma_f32_32x32x16_bf16(af1[j], breg##CUR[e][j], accE[e][1], 0, 0, 0); \
        }                                                                         \
    }                                                                             \
    __syncthreads(); }

    #pragma unroll 1
    for (int ks = 0; ks < NST - 1; ks += 2) {
        GSTEP(0, 1, ks)
        GSTEP(1, 0, ks + 1)
    }
    GSTEP(0, 1, NST - 1)
#undef GSTEP

    const int ncol = nblkg * 32 + (l & 31);
    #pragma unroll
    for (int m = 0; m < 2; ++m) {
        #pragma unroll
        for (int g = 0; g < 16; ++g) {
            const int rloc = (g & 3) + 8 * (g >> 2) + 4 * (l >> 5);
            const int row = wr * 64 + m * 32 + rloc;
            float v = 0.f;
            #pragma unroll
            for (int e = 0; e < EPB; ++e) v = fmaf(coeffT[e][row], accE[e][m][g], v);
            P[((size_t)part * BATCH + b0 + row) * OUTW + ncol] = v;
        }
    }
}

// ---------------------------------------------------------------------------
extern "C" void kernel_launch(void* const* d_in, const int* in_sizes, int n_in,
                              void* d_out, int out_size, void* d_ws, size_t ws_size,
                              hipStream_t stream) {
    const float* z   = (const float*)d_in[0];
    const float* c   = (const float*)d_in[1];
    const float* w0  = (const float*)d_in[2];
    const float* b0  = (const float*)d_in[3];
    const float* w1  = (const float*)d_in[4];
    const float* b1  = (const float*)d_in[5];
    const float* w2  = (const float*)d_in[6];
    const float* b2  = (const float*)d_in[7];
    const float* gw0 = (const float*)d_in[8];
    const float* gb0 = (const float*)d_in[9];
    const float* gc0 = (const float*)d_in[10];
    const float* gw1 = (const float*)d_in[11];
    const float* gb1 = (const float*)d_in[12];
    const float* gc1 = (const float*)d_in[13];
    const float* gw2 = (const float*)d_in[14];
    const float* gb2 = (const float*)d_in[15];
    const float* gc2 = (const float*)d_in[16];
    float* out = (float*)d_out;

    char* p = (char*)d_ws;
    float* coeff = (float*)p;  p += (size_t)BATCH * EXPERTS * 4;
    float* gW0t  = (float*)p;  p += (size_t)GATE_H * IN_DIM * 4;
    float* gW1t  = (float*)p;  p += (size_t)GATE_H * GATE_H * 4;
    float* gW2t  = (float*)p;  p += (size_t)EXPERTS * GATE_H * 4;
    u16* Apk0 = (u16*)p;       p += (size_t)128 * 60 * 1024;
    u16* Apk1 = (u16*)p;       p += (size_t)128 * 108 * 1024;
    u16* Apk2 = (u16*)p;       p += (size_t)128 * 108 * 1024;
    u16* Bpk0 = (u16*)p;       p += (size_t)16 * 8 * 60 * 1024;
    u16* Bpk1 = (u16*)p;       p += (size_t)16 * 8 * 108 * 1024;
    u16* Bpk2 = (u16*)p;       p += (size_t)1 * 8 * 108 * 1024;
    float* P  = (float*)p;     p += (size_t)4 * BATCH * HIDDEN * 4;

    // gate (transposed scaled weights + 4-samples/block MLP)
    scale_rows_t_kernel<<<GATE_H, 64, 0, stream>>>(gw0, gc0, gW0t, IN_DIM, GATE_H);
    scale_rows_t_kernel<<<GATE_H, 64, 0, stream>>>(gw1, gc1, gW1t, GATE_H, GATE_H);
    scale_rows_t_kernel<<<EXPERTS, 64, 0, stream>>>(gw2, gc2, gW2t, GATE_H, EXPERTS);
    gate_forward_v2<<<BATCH / GS, 128, 0, stream>>>(z, c, gW0t, gb0, gW1t, gb1,
                                                    gW2t, gb2, coeff);

    // weight packing
    wprep_kernel<IN_DIM, HIDDEN><<<dim3(EXPERTS, 16), 256, 0, stream>>>(w0, Bpk0);
    wprep_kernel<INTER,  HIDDEN><<<dim3(EXPERTS, 16), 256, 0, stream>>>(w1, Bpk1);
    wprep_kernel<INTER, ACTIONS><<<dim3(EXPERTS, 1), 256, 0, stream>>>(w2, Bpk2);

    // activation packing
    amat0_kernel<<<128, 256, 0, stream>>>(z, c, Apk0);
    zpack_kernel<<<128, 256, 0, stream>>>(z, Apk1, Apk2);

    // layer 0
    moe_gemm<20, 2, 2, HIDDEN><<<dim3(32, 8, 4), 256, 0, stream>>>(Apk0, Bpk0, coeff, P);
    reduce_pack_kernel<4><<<128, 256, 0, stream>>>(P, coeff, b0, Apk1);

    // layer 1
    moe_gemm<36, 2, 2, HIDDEN><<<dim3(32, 8, 4), 256, 0, stream>>>(Apk1, Bpk1, coeff, P);
    reduce_pack_kernel<4><<<128, 256, 0, stream>>>(P, coeff, b1, Apk2);

    // layer 2
    moe_gemm<36, 1, 1, 32><<<dim3(32, 1, 8), 128, 0, stream>>>(Apk2, Bpk2, coeff, P);
    reduce_out_kernel<<<128, 256, 0, stream>>>(P, coeff, b2, out);
}

// Round 5
// 207.025 us; speedup vs baseline: 5.0651x; 1.3046x over previous
//
#include <hip/hip_runtime.h>
#include <hip/hip_bf16.h>
#include <hip/hip_fp16.h>
#include <math.h>

#define BATCH 4096
#define INPUT_SIZE 256
#define LATENT 64
#define HIDDEN 512
#define ACTIONS 12
#define EXPERTS 8
#define GATE_H 128
#define IN_DIM (INPUT_SIZE + LATENT)   // 320
#define INTER (HIDDEN + LATENT)        // 576

typedef unsigned int u32;
typedef unsigned short u16;
typedef __attribute__((ext_vector_type(8))) short short8;
typedef __attribute__((ext_vector_type(8))) _Float16 f16x8;
typedef __attribute__((ext_vector_type(4))) float f32x4;
typedef __attribute__((ext_vector_type(16))) float f32x16;

__device__ __forceinline__ u16 f2h(float x) { return __half_as_ushort(__float2half(x)); }
__device__ __forceinline__ float h2f(u16 u) { return __half2float(__ushort_as_half(u)); }

__device__ __forceinline__ void gload16(const void* g, void* lds) {
    __builtin_amdgcn_global_load_lds(
        (const __attribute__((address_space(1))) u32*)g,
        (__attribute__((address_space(3))) u32*)lds, 16, 0, 0);
}

// ---------------------------------------------------------------------------
// Fused Lipschitz row scaling for all 3 gate layers (transposed output)
// blocks 0..127 -> W0 (320 cols), 128..255 -> W1 (128), 256..263 -> W2 (128)
// ---------------------------------------------------------------------------
__global__ void scale_all_kernel(
    const float* __restrict__ gw0, const float* __restrict__ gc0, float* __restrict__ W0t,
    const float* __restrict__ gw1, const float* __restrict__ gc1, float* __restrict__ W1t,
    const float* __restrict__ gw2, const float* __restrict__ gc2, float* __restrict__ W2t) {
    const int bid = blockIdx.x;
    const float* W; const float* cc; float* Wt; int cols, rows, row;
    if (bid < 128)      { W = gw0; cc = gc0; Wt = W0t; cols = IN_DIM; rows = GATE_H; row = bid; }
    else if (bid < 256) { W = gw1; cc = gc1; Wt = W1t; cols = GATE_H; rows = GATE_H; row = bid - 128; }
    else                { W = gw2; cc = gc2; Wt = W2t; cols = GATE_H; rows = EXPERTS; row = bid - 256; }
    const float* w = W + (size_t)row * cols;
    float s = 0.f;
    for (int i = threadIdx.x; i < cols; i += 64) s += fabsf(w[i]);
    #pragma unroll
    for (int off = 32; off > 0; off >>= 1) s += __shfl_down(s, off, 64);
    s = __shfl(s, 0, 64);
    const float cv = cc[0];
    const float lipc = (cv > 0.f) ? (cv + log1pf(expf(-cv))) : log1pf(expf(cv));
    const float scale = fminf(lipc / s, 1.0f);
    for (int i = threadIdx.x; i < cols; i += 64)
        Wt[(size_t)i * rows + row] = w[i] * scale;
}

// ---------------------------------------------------------------------------
// Gate MLP: 4 samples/block, transposed weights (verified round 3)
// ---------------------------------------------------------------------------
#define GS 4
__global__ __launch_bounds__(128) void gate_forward_v2(
    const float* __restrict__ z, const float* __restrict__ c,
    const float* __restrict__ W0t, const float* __restrict__ b0,
    const float* __restrict__ W1t, const float* __restrict__ b1,
    const float* __restrict__ W2t, const float* __restrict__ b2,
    float* __restrict__ coeff) {
    __shared__ float xs[GS][IN_DIM + 1];
    __shared__ float h1s[GS][GATE_H + 1];
    __shared__ float h2s[GS][GATE_H + 1];
    __shared__ float red[GS][EXPERTS];

    const int b4 = blockIdx.x * GS;
    const int t = threadIdx.x;

    for (int idx = t; idx < GS * IN_DIM; idx += 128) {
        const int s = idx / IN_DIM, i = idx - s * IN_DIM;
        xs[s][i] = (i < LATENT) ? z[(size_t)(b4 + s) * LATENT + i]
                                : c[(size_t)(b4 + s) * INPUT_SIZE + (i - LATENT)];
    }
    __syncthreads();
    {
        float acc[GS];
        #pragma unroll
        for (int s = 0; s < GS; ++s) acc[s] = b0[t];
        #pragma unroll 4
        for (int i = 0; i < IN_DIM; ++i) {
            const float wv = W0t[(size_t)i * GATE_H + t];
            #pragma unroll
            for (int s = 0; s < GS; ++s) acc[s] = fmaf(xs[s][i], wv, acc[s]);
        }
        #pragma unroll
        for (int s = 0; s < GS; ++s)
            h1s[s][t] = acc[s] > 0.f ? acc[s] : expm1f(acc[s]);
    }
    __syncthreads();
    {
        float acc[GS];
        #pragma unroll
        for (int s = 0; s < GS; ++s) acc[s] = b1[t];
        #pragma unroll 4
        for (int i = 0; i < GATE_H; ++i) {
            const float wv = W1t[(size_t)i * GATE_H + t];
            #pragma unroll
            for (int s = 0; s < GS; ++s) acc[s] = fmaf(h1s[s][i], wv, acc[s]);
        }
        #pragma unroll
        for (int s = 0; s < GS; ++s)
            h2s[s][t] = acc[s] > 0.f ? acc[s] : expm1f(acc[s]);
    }
    __syncthreads();
    if (t < GS * EXPERTS) {
        const int s = t >> 3, e = t & 7;
        float acc = b2[e];
        #pragma unroll 4
        for (int i = 0; i < GATE_H; ++i)
            acc = fmaf(h2s[s][i], W2t[(size_t)i * EXPERTS + e], acc);
        red[s][e] = acc;
    }
    __syncthreads();
    if (t < GS) {
        float m = red[t][0];
        #pragma unroll
        for (int i = 1; i < EXPERTS; ++i) m = fmaxf(m, red[t][i]);
        float e[EXPERTS];
        float sum = 0.f;
        #pragma unroll
        for (int i = 0; i < EXPERTS; ++i) { e[i] = expf(red[t][i] - m); sum += e[i]; }
        const float inv = 1.f / sum;
        #pragma unroll
        for (int i = 0; i < EXPERTS; ++i)
            coeff[(size_t)(b4 + t) * EXPERTS + i] = e[i] * inv;
    }
}

// ---------------------------------------------------------------------------
// B prep: w (E, IN, OUT) f32 -> frag-packed f16, SINGLE plane [NK ksubs]
// chunk ksub jj: lane l holds w[e][jj*16 + (l>>5)*8 + i][nblk*32 + (l&31)]
// ---------------------------------------------------------------------------
template<int IN, int OUT>
__global__ __launch_bounds__(256) void wprep_kernel(const float* __restrict__ w,
                                                    u16* __restrict__ Bpk) {
    constexpr int NK = IN / 16;
    __shared__ float tile[4][16][33];
    const int t = threadIdx.x, wv = t >> 6, l = t & 63;
    const int e = blockIdx.x, nblk = blockIdx.y, n0 = nblk * 32;
    const int col = l & 31, half = l >> 5;
    char* base = (char*)Bpk + ((size_t)(nblk * EXPERTS + e) * NK) * 1024;

    for (int jj = wv; jj < NK; jj += 4) {
        #pragma unroll
        for (int i = 0; i < 8; ++i) {
            const int r = i * 2 + half;
            float v = 0.f;
            if (n0 + col < OUT) v = w[((size_t)e * IN + jj * 16 + r) * OUT + n0 + col];
            tile[wv][r][col] = v;
        }
        short8 hh;
        #pragma unroll
        for (int i = 0; i < 8; ++i)
            hh[i] = (short)f2h(tile[wv][half * 8 + i][col]);
        *(short8*)(base + (size_t)jj * 1024 + l * 16) = hh;
    }
}

// ---------------------------------------------------------------------------
// A prep fused: layer0 planes [xh | xl] (NK0=20) + z-parts of Apk1/Apk2
// (NK1=36: ksubs 0..3 and 36..39)
// ---------------------------------------------------------------------------
__global__ __launch_bounds__(256) void apack_kernel(const float* __restrict__ z,
                                                    const float* __restrict__ c,
                                                    u16* __restrict__ Apk0,
                                                    u16* __restrict__ Apk1,
                                                    u16* __restrict__ Apk2) {
    constexpr int NK0 = 20, NK1 = 36;
    const int t = threadIdx.x, wv = t >> 6, l = t & 63;
    const int bblk = blockIdx.x;
    const int r = l & 31, half = l >> 5;
    const int row = bblk * 32 + r;
    char* base0 = (char*)Apk0 + (size_t)bblk * (2 * NK0) * 1024;
    char* base1 = (char*)Apk1 + (size_t)bblk * (2 * NK1) * 1024;
    char* base2 = (char*)Apk2 + (size_t)bblk * (2 * NK1) * 1024;

    for (int jj = wv; jj < NK0; jj += 4) {
        const int k = jj * 16 + half * 8;
        const float* src = (k < LATENT) ? (z + (size_t)row * LATENT + k)
                                        : (c + (size_t)row * INPUT_SIZE + (k - LATENT));
        short8 hh, ll;
        #pragma unroll
        for (int i = 0; i < 8; ++i) {
            const float v = src[i];
            const u16 hb = f2h(v);
            hh[i] = (short)hb;
            ll[i] = (short)f2h(v - h2f(hb));
        }
        *(short8*)(base0 + (size_t)jj * 1024 + l * 16) = hh;
        *(short8*)(base0 + (size_t)(NK0 + jj) * 1024 + l * 16) = ll;
        if (jj < 4) {   // z-part for layers 1/2
            *(short8*)(base1 + (size_t)jj * 1024 + l * 16) = hh;
            *(short8*)(base1 + (size_t)(NK1 + jj) * 1024 + l * 16) = ll;
            *(short8*)(base2 + (size_t)jj * 1024 + l * 16) = hh;
            *(short8*)(base2 + (size_t)(NK1 + jj) * 1024 + l * 16) = ll;
        }
    }
}

// ---------------------------------------------------------------------------
// Reduce split-K partials + coeff-mixed bias + ELU -> packed A (f16 hi/lo)
// grid (128, 2): 32 rows x 256-col half per block
// ---------------------------------------------------------------------------
template<int NPART>
__global__ __launch_bounds__(256) void reduce_pack_kernel(
    const float* __restrict__ P, const float* __restrict__ coeff,
    const float* __restrict__ bias, u16* __restrict__ ApkNext) {
    constexpr int NK = 36;
    __shared__ float biasS[EXPERTS][256];
    __shared__ float coeffS[32][9];
    const int t = threadIdx.x, wv = t >> 6, l = t & 63;
    const int bblk = blockIdx.x, ch = blockIdx.y;
    const int r = l & 31, half = l >> 5;
    const int row = bblk * 32 + r;

    for (int idx = t; idx < EXPERTS * 256; idx += 256)
        biasS[idx >> 8][idx & 255] = bias[(idx >> 8) * HIDDEN + ch * 256 + (idx & 255)];
    for (int idx = t; idx < 32 * 8; idx += 256)
        coeffS[idx >> 3][idx & 7] = coeff[(size_t)(bblk * 32 + (idx >> 3)) * 8 + (idx & 7)];
    __syncthreads();

    char* base = (char*)ApkNext + (size_t)bblk * (2 * NK) * 1024;
    for (int jj = ch * 16 + wv; jj < ch * 16 + 16; jj += 4) {
        const int cb = jj * 16 + half * 8;
        float v[8];
        #pragma unroll
        for (int i = 0; i < 8; ++i) v[i] = 0.f;
        #pragma unroll
        for (int p = 0; p < NPART; ++p) {
            const float4* q = (const float4*)(P + ((size_t)p * BATCH + row) * HIDDEN + cb);
            const float4 a = q[0], b = q[1];
            v[0] += a.x; v[1] += a.y; v[2] += a.z; v[3] += a.w;
            v[4] += b.x; v[5] += b.y; v[6] += b.z; v[7] += b.w;
        }
        #pragma unroll
        for (int e = 0; e < EXPERTS; ++e) {
            const float cv = coeffS[r][e];
            #pragma unroll
            for (int i = 0; i < 8; ++i) v[i] = fmaf(cv, biasS[e][cb - ch * 256 + i], v[i]);
        }
        short8 hh, ll;
        #pragma unroll
        for (int i = 0; i < 8; ++i) {
            const float hv = v[i] > 0.f ? v[i] : expm1f(v[i]);
            const u16 hb = f2h(hv);
            hh[i] = (short)hb;
            ll[i] = (short)f2h(hv - h2f(hb));
        }
        *(short8*)(base + (size_t)(4 + jj) * 1024 + l * 16) = hh;
        *(short8*)(base + (size_t)(NK + 4 + jj) * 1024 + l * 16) = ll;
    }
}

// ---------------------------------------------------------------------------
// Final reduce: 8 partials + coeff-mixed bias, OUT=12
// ---------------------------------------------------------------------------
__global__ __launch_bounds__(256) void reduce_out_kernel(
    const float* __restrict__ P2, const float* __restrict__ coeff,
    const float* __restrict__ b2, float* __restrict__ out) {
    const int t = threadIdx.x;
    const int bblk = blockIdx.x;
    for (int idx = t; idx < 32 * ACTIONS; idx += 256) {
        const int r = idx / ACTIONS, n = idx % ACTIONS;
        const int row = bblk * 32 + r;
        float s = 0.f;
        #pragma unroll
        for (int p = 0; p < 8; ++p) s += P2[((size_t)p * BATCH + row) * 32 + n];
        const float* cf = coeff + (size_t)row * 8;
        #pragma unroll
        for (int e = 0; e < 8; ++e) s = fmaf(cf[e], b2[e * ACTIONS + n], s);
        out[(size_t)row * ACTIONS + n] = s;
    }
}

// ---------------------------------------------------------------------------
// MoE GEMM, f16 2-plane: A planes [xh | xl] (2*NK ksubs), B single plane
// (NK ksubs, walked twice). Tile 128 x (32*WN), waves 2 x WN, 32x32x16 f16.
// XCD-aware block remap: each XCD gets a contiguous x-chunk (A L2-resident).
// ---------------------------------------------------------------------------
template<int NK, int WN, int EPB, int OUTW, int GX, int GY, int GZ>
__global__ __launch_bounds__(128 * WN) void moe_gemm(
    const u16* __restrict__ Apk, const u16* __restrict__ Bpk,
    const float* __restrict__ coeff, float* __restrict__ P) {
    constexpr int NST = NK / 2;           // K-steps (of 64 k) over both planes
    constexpr int BHALF = NST / 2;        // steps per B-plane walk
    constexpr int NWAVE = 2 * WN;
    constexpr int CPW = 16 / NWAVE;
    constexpr int CPX = GX / 8;

    __shared__ __align__(16) char As[32768];
    __shared__ float coeffT[EPB][128];

    const int t = threadIdx.x, wv = t >> 6, l = t & 63;
    const int wr = wv & 1, wc = wv >> 1;

    // XCD remap: fid%8 = XCD (round-robin); give each XCD a contiguous x-chunk
    const int fid = blockIdx.x + GX * (blockIdx.y + GY * blockIdx.z);
    const int xcd = fid & 7, idx = fid >> 3;
    const int bx = xcd * CPX + (idx % CPX);
    const int yz = idx / CPX;
    const int by = yz % GY, bz = yz / GY;

    const int b0 = bx * 128;
    const int bblk0 = bx * 4;
    const int nblkg = by * WN + wc;
    const int part = bz;
    const int estart = part * EPB;

    for (int idx2 = t; idx2 < EPB * 128; idx2 += 128 * WN)
        coeffT[idx2 >> 7][idx2 & 127] =
            coeff[(size_t)(b0 + (idx2 & 127)) * EXPERTS + estart + (idx2 >> 7)];

    const char* Ab = (const char*)Apk;
    const char* Bbase[EPB];
    #pragma unroll
    for (int e = 0; e < EPB; ++e)
        Bbase[e] = (const char*)Bpk +
                   ((size_t)(nblkg * EXPERTS + estart + e) * NK) * 1024 + l * 16;

    f32x16 accE[EPB][2];
    #pragma unroll
    for (int e = 0; e < EPB; ++e) { accE[e][0] = (f32x16)0.f; accE[e][1] = (f32x16)0.f; }

    f16x8 breg0[EPB][4], breg1[EPB][4];

    // prologue: stage step 0
    #pragma unroll
    for (int q = 0; q < CPW; ++q) {
        const int cf = wv * CPW + q, bb = cf >> 2, kq = cf & 3;
        gload16(Ab + ((size_t)(bblk0 + bb) * (2 * NK) + kq) * 1024 + l * 16,
                As + cf * 1024 + l * 16);
    }
    #pragma unroll
    for (int e = 0; e < EPB; ++e)
        #pragma unroll
        for (int q = 0; q < 4; ++q)
            breg0[e][q] = *(const f16x8*)(Bbase[e] + q * 1024);
    __syncthreads();

#define GSTEP(CUR, NXT, KS) {                                                     \
    if ((KS) + 1 < NST) {                                                         \
        const int nks = (KS) + 1;                                                 \
        const int bks = (nks < BHALF) ? nks : nks - BHALF;                        \
        _Pragma("unroll")                                                         \
        for (int q = 0; q < CPW; ++q) {                                           \
            const int cf = wv * CPW + q, bb = cf >> 2, kq = cf & 3;               \
            gload16(Ab + ((size_t)(bblk0 + bb) * (2 * NK) + nks * 4 + kq) * 1024 + l * 16, \
                    As + (NXT) * 16384 + cf * 1024 + l * 16);                     \
        }                                                                         \
        _Pragma("unroll")                                                         \
        for (int e = 0; e < EPB; ++e) {                                           \
            _Pragma("unroll")                                                     \
            for (int q = 0; q < 4; ++q)                                           \
                breg##NXT[e][q] = *(const f16x8*)(Bbase[e] + (size_t)bks * 4096 + q * 1024); \
        }                                                                         \
    }                                                                             \
    f16x8 af0[4], af1[4];                                                         \
    _Pragma("unroll")                                                             \
    for (int j = 0; j < 4; ++j) {                                                 \
        af0[j] = *(const f16x8*)(As + (CUR) * 16384 + ((wr * 2 + 0) * 4 + j) * 1024 + l * 16); \
        af1[j] = *(const f16x8*)(As + (CUR) * 16384 + ((wr * 2 + 1) * 4 + j) * 1024 + l * 16); \
    }                                                                             \
    _Pragma("unroll")                                                             \
    for (int e = 0; e < EPB; ++e) {                                               \
        _Pragma("unroll")                                                         \
        for (int j = 0; j < 4; ++j) {                                             \
            accE[e][0] = __builtin_amdgcn_mfma_f32_32x32x16_f16(af0[j], breg##CUR[e][j], accE[e][0], 0, 0, 0); \
            accE[e][1] = __builtin_amdgcn_mfma_f32_32x32x16_f16(af1[j], breg##CUR[e][j], accE[e][1], 0, 0, 0); \
        }                                                                         \
    }                                                                             \
    __syncthreads(); }

    // NST is even for all instantiations (10, 18)
    #pragma unroll 1
    for (int ks = 0; ks < NST; ks += 2) {
        GSTEP(0, 1, ks)
        GSTEP(1, 0, ks + 1)
    }
#undef GSTEP

    const int ncol = nblkg * 32 + (l & 31);
    #pragma unroll
    for (int m = 0; m < 2; ++m) {
        #pragma unroll
        for (int g = 0; g < 16; ++g) {
            const int rloc = (g & 3) + 8 * (g >> 2) + 4 * (l >> 5);
            const int row = wr * 64 + m * 32 + rloc;
            float v = 0.f;
            #pragma unroll
            for (int e = 0; e < EPB; ++e) v = fmaf(coeffT[e][row], accE[e][m][g], v);
            P[((size_t)part * BATCH + b0 + row) * OUTW + ncol] = v;
        }
    }
}

// ---------------------------------------------------------------------------
extern "C" void kernel_launch(void* const* d_in, const int* in_sizes, int n_in,
                              void* d_out, int out_size, void* d_ws, size_t ws_size,
                              hipStream_t stream) {
    const float* z   = (const float*)d_in[0];
    const float* c   = (const float*)d_in[1];
    const float* w0  = (const float*)d_in[2];
    const float* b0  = (const float*)d_in[3];
    const float* w1  = (const float*)d_in[4];
    const float* b1  = (const float*)d_in[5];
    const float* w2  = (const float*)d_in[6];
    const float* b2  = (const float*)d_in[7];
    const float* gw0 = (const float*)d_in[8];
    const float* gb0 = (const float*)d_in[9];
    const float* gc0 = (const float*)d_in[10];
    const float* gw1 = (const float*)d_in[11];
    const float* gb1 = (const float*)d_in[12];
    const float* gc1 = (const float*)d_in[13];
    const float* gw2 = (const float*)d_in[14];
    const float* gb2 = (const float*)d_in[15];
    const float* gc2 = (const float*)d_in[16];
    float* out = (float*)d_out;

    char* p = (char*)d_ws;
    float* coeff = (float*)p;  p += (size_t)BATCH * EXPERTS * 4;
    float* gW0t  = (float*)p;  p += (size_t)GATE_H * IN_DIM * 4;
    float* gW1t  = (float*)p;  p += (size_t)GATE_H * GATE_H * 4;
    float* gW2t  = (float*)p;  p += (size_t)EXPERTS * GATE_H * 4;
    u16* Apk0 = (u16*)p;       p += (size_t)128 * 40 * 1024;      // 5 MB
    u16* Apk1 = (u16*)p;       p += (size_t)128 * 72 * 1024;      // 9 MB
    u16* Apk2 = (u16*)p;       p += (size_t)128 * 72 * 1024;      // 9 MB
    u16* Bpk0 = (u16*)p;       p += (size_t)16 * 8 * 20 * 1024;   // 2.5 MB
    u16* Bpk1 = (u16*)p;       p += (size_t)16 * 8 * 36 * 1024;   // 4.5 MB
    u16* Bpk2 = (u16*)p;       p += (size_t)1 * 8 * 36 * 1024;    // 0.3 MB
    float* P  = (float*)p;     p += (size_t)4 * BATCH * HIDDEN * 4;

    // gate
    scale_all_kernel<<<264, 64, 0, stream>>>(gw0, gc0, gW0t, gw1, gc1, gW1t,
                                             gw2, gc2, gW2t);
    gate_forward_v2<<<BATCH / GS, 128, 0, stream>>>(z, c, gW0t, gb0, gW1t, gb1,
                                                    gW2t, gb2, coeff);

    // weight packing (single f16 plane)
    wprep_kernel<IN_DIM, HIDDEN><<<dim3(EXPERTS, 16), 256, 0, stream>>>(w0, Bpk0);
    wprep_kernel<INTER,  HIDDEN><<<dim3(EXPERTS, 16), 256, 0, stream>>>(w1, Bpk1);
    wprep_kernel<INTER, ACTIONS><<<dim3(EXPERTS, 1), 256, 0, stream>>>(w2, Bpk2);

    // activation packing (layer0 + z-parts of layers 1/2)
    apack_kernel<<<128, 256, 0, stream>>>(z, c, Apk0, Apk1, Apk2);

    // layer 0: NK=20, NST=10
    moe_gemm<20, 2, 2, HIDDEN, 32, 8, 4><<<dim3(32, 8, 4), 256, 0, stream>>>(
        Apk0, Bpk0, coeff, P);
    reduce_pack_kernel<4><<<dim3(128, 2), 256, 0, stream>>>(P, coeff, b0, Apk1);

    // layer 1: NK=36, NST=18
    moe_gemm<36, 2, 2, HIDDEN, 32, 8, 4><<<dim3(32, 8, 4), 256, 0, stream>>>(
        Apk1, Bpk1, coeff, P);
    reduce_pack_kernel<4><<<dim3(128, 2), 256, 0, stream>>>(P, coeff, b1, Apk2);

    // layer 2: NK=36, OUT padded to 32, split-K 8
    moe_gemm<36, 1, 1, 32, 32, 1, 8><<<dim3(32, 1, 8), 128, 0, stream>>>(
        Apk2, Bpk2, coeff, P);
    reduce_out_kernel<<<128, 256, 0, stream>>>(P, coeff, b2, out);
}

// Round 6
// 169.023 us; speedup vs baseline: 6.2040x; 1.2248x over previous
//
#include <hip/hip_runtime.h>
#include <hip/hip_bf16.h>
#include <hip/hip_fp16.h>
#include <math.h>

#define BATCH 4096
#define INPUT_SIZE 256
#define LATENT 64
#define HIDDEN 512
#define ACTIONS 12
#define EXPERTS 8
#define GATE_H 128
#define IN_DIM (INPUT_SIZE + LATENT)   // 320
#define INTER (HIDDEN + LATENT)        // 576

typedef unsigned int u32;
typedef unsigned short u16;
typedef __attribute__((ext_vector_type(8))) short short8;
typedef __attribute__((ext_vector_type(8))) _Float16 f16x8;
typedef __attribute__((ext_vector_type(16))) float f32x16;

__device__ __forceinline__ u16 f2h(float x) { return __half_as_ushort(__float2half(x)); }
__device__ __forceinline__ float h2f(u16 u) { return __half2float(__ushort_as_half(u)); }

__device__ __forceinline__ void gload16(const void* g, void* lds) {
    __builtin_amdgcn_global_load_lds(
        (const __attribute__((address_space(1))) u32*)g,
        (__attribute__((address_space(3))) u32*)lds, 16, 0, 0);
}

// ---------------------------------------------------------------------------
// Fused Lipschitz row scaling for all 3 gate layers (transposed output)
// ---------------------------------------------------------------------------
__global__ void scale_all_kernel(
    const float* __restrict__ gw0, const float* __restrict__ gc0, float* __restrict__ W0t,
    const float* __restrict__ gw1, const float* __restrict__ gc1, float* __restrict__ W1t,
    const float* __restrict__ gw2, const float* __restrict__ gc2, float* __restrict__ W2t) {
    const int bid = blockIdx.x;
    const float* W; const float* cc; float* Wt; int cols, rows, row;
    if (bid < 128)      { W = gw0; cc = gc0; Wt = W0t; cols = IN_DIM; rows = GATE_H; row = bid; }
    else if (bid < 256) { W = gw1; cc = gc1; Wt = W1t; cols = GATE_H; rows = GATE_H; row = bid - 128; }
    else                { W = gw2; cc = gc2; Wt = W2t; cols = GATE_H; rows = EXPERTS; row = bid - 256; }
    const float* w = W + (size_t)row * cols;
    float s = 0.f;
    for (int i = threadIdx.x; i < cols; i += 64) s += fabsf(w[i]);
    #pragma unroll
    for (int off = 32; off > 0; off >>= 1) s += __shfl_down(s, off, 64);
    s = __shfl(s, 0, 64);
    const float cv = cc[0];
    const float lipc = (cv > 0.f) ? (cv + log1pf(expf(-cv))) : log1pf(expf(cv));
    const float scale = fminf(lipc / s, 1.0f);
    for (int i = threadIdx.x; i < cols; i += 64)
        Wt[(size_t)i * rows + row] = w[i] * scale;
}

// ---------------------------------------------------------------------------
// Gate MLP: 8 samples/block, transposed weights
// ---------------------------------------------------------------------------
#define GS 8
__global__ __launch_bounds__(128) void gate_forward_v2(
    const float* __restrict__ z, const float* __restrict__ c,
    const float* __restrict__ W0t, const float* __restrict__ b0,
    const float* __restrict__ W1t, const float* __restrict__ b1,
    const float* __restrict__ W2t, const float* __restrict__ b2,
    float* __restrict__ coeff) {
    __shared__ float xs[GS][IN_DIM + 1];
    __shared__ float h1s[GS][GATE_H + 1];
    __shared__ float h2s[GS][GATE_H + 1];
    __shared__ float red[GS][EXPERTS];

    const int b4 = blockIdx.x * GS;
    const int t = threadIdx.x;

    for (int idx = t; idx < GS * IN_DIM; idx += 128) {
        const int s = idx / IN_DIM, i = idx - s * IN_DIM;
        xs[s][i] = (i < LATENT) ? z[(size_t)(b4 + s) * LATENT + i]
                                : c[(size_t)(b4 + s) * INPUT_SIZE + (i - LATENT)];
    }
    __syncthreads();
    {
        float acc[GS];
        #pragma unroll
        for (int s = 0; s < GS; ++s) acc[s] = b0[t];
        #pragma unroll 4
        for (int i = 0; i < IN_DIM; ++i) {
            const float wv = W0t[(size_t)i * GATE_H + t];
            #pragma unroll
            for (int s = 0; s < GS; ++s) acc[s] = fmaf(xs[s][i], wv, acc[s]);
        }
        #pragma unroll
        for (int s = 0; s < GS; ++s)
            h1s[s][t] = acc[s] > 0.f ? acc[s] : expm1f(acc[s]);
    }
    __syncthreads();
    {
        float acc[GS];
        #pragma unroll
        for (int s = 0; s < GS; ++s) acc[s] = b1[t];
        #pragma unroll 4
        for (int i = 0; i < GATE_H; ++i) {
            const float wv = W1t[(size_t)i * GATE_H + t];
            #pragma unroll
            for (int s = 0; s < GS; ++s) acc[s] = fmaf(h1s[s][i], wv, acc[s]);
        }
        #pragma unroll
        for (int s = 0; s < GS; ++s)
            h2s[s][t] = acc[s] > 0.f ? acc[s] : expm1f(acc[s]);
    }
    __syncthreads();
    if (t < GS * EXPERTS) {
        const int s = t >> 3, e = t & 7;
        float acc = b2[e];
        #pragma unroll 4
        for (int i = 0; i < GATE_H; ++i)
            acc = fmaf(h2s[s][i], W2t[(size_t)i * EXPERTS + e], acc);
        red[s][e] = acc;
    }
    __syncthreads();
    if (t < GS) {
        float m = red[t][0];
        #pragma unroll
        for (int i = 1; i < EXPERTS; ++i) m = fmaxf(m, red[t][i]);
        float e[EXPERTS];
        float sum = 0.f;
        #pragma unroll
        for (int i = 0; i < EXPERTS; ++i) { e[i] = expf(red[t][i] - m); sum += e[i]; }
        const float inv = 1.f / sum;
        #pragma unroll
        for (int i = 0; i < EXPERTS; ++i)
            coeff[(size_t)(b4 + t) * EXPERTS + i] = e[i] * inv;
    }
}

// ---------------------------------------------------------------------------
// B prep: w (E, IN, OUT) f32 -> frag-packed f16 single plane [NK ksubs]
// ---------------------------------------------------------------------------
template<int IN, int OUT>
__global__ __launch_bounds__(256) void wprep_kernel(const float* __restrict__ w,
                                                    u16* __restrict__ Bpk) {
    constexpr int NK = IN / 16;
    __shared__ float tile[4][16][33];
    const int t = threadIdx.x, wv = t >> 6, l = t & 63;
    const int e = blockIdx.x, nblk = blockIdx.y, n0 = nblk * 32;
    const int col = l & 31, half = l >> 5;
    char* base = (char*)Bpk + ((size_t)(nblk * EXPERTS + e) * NK) * 1024;

    for (int jj = wv; jj < NK; jj += 4) {
        #pragma unroll
        for (int i = 0; i < 8; ++i) {
            const int r = i * 2 + half;
            float v = 0.f;
            if (n0 + col < OUT) v = w[((size_t)e * IN + jj * 16 + r) * OUT + n0 + col];
            tile[wv][r][col] = v;
        }
        short8 hh;
        #pragma unroll
        for (int i = 0; i < 8; ++i)
            hh[i] = (short)f2h(tile[wv][half * 8 + i][col]);
        *(short8*)(base + (size_t)jj * 1024 + l * 16) = hh;
    }
}

// ---------------------------------------------------------------------------
// A prep: layer0 single plane (NK0=20) + z-parts (ksubs 0..3) of Apk1/Apk2
// ---------------------------------------------------------------------------
__global__ __launch_bounds__(256) void apack_kernel(const float* __restrict__ z,
                                                    const float* __restrict__ c,
                                                    u16* __restrict__ Apk0,
                                                    u16* __restrict__ Apk1,
                                                    u16* __restrict__ Apk2) {
    constexpr int NK0 = 20, NK1 = 36;
    const int t = threadIdx.x, wv = t >> 6, l = t & 63;
    const int bblk = blockIdx.x;
    const int r = l & 31, half = l >> 5;
    const int row = bblk * 32 + r;
    char* base0 = (char*)Apk0 + (size_t)bblk * NK0 * 1024;
    char* base1 = (char*)Apk1 + (size_t)bblk * NK1 * 1024;
    char* base2 = (char*)Apk2 + (size_t)bblk * NK1 * 1024;

    for (int jj = wv; jj < NK0; jj += 4) {
        const int k = jj * 16 + half * 8;
        const float* src = (k < LATENT) ? (z + (size_t)row * LATENT + k)
                                        : (c + (size_t)row * INPUT_SIZE + (k - LATENT));
        short8 hh;
        #pragma unroll
        for (int i = 0; i < 8; ++i) hh[i] = (short)f2h(src[i]);
        *(short8*)(base0 + (size_t)jj * 1024 + l * 16) = hh;
        if (jj < 4) {
            *(short8*)(base1 + (size_t)jj * 1024 + l * 16) = hh;
            *(short8*)(base2 + (size_t)jj * 1024 + l * 16) = hh;
        }
    }
}

// ---------------------------------------------------------------------------
// Reduce split-K partials + coeff-mixed bias + ELU -> packed next-A (f16)
// ---------------------------------------------------------------------------
template<int NPART>
__global__ __launch_bounds__(256) void reduce_pack_kernel(
    const float* __restrict__ P, const float* __restrict__ coeff,
    const float* __restrict__ bias, u16* __restrict__ ApkNext) {
    constexpr int NK = 36;
    __shared__ float biasS[EXPERTS][256];
    __shared__ float coeffS[32][9];
    const int t = threadIdx.x, wv = t >> 6, l = t & 63;
    const int bblk = blockIdx.x, ch = blockIdx.y;
    const int r = l & 31, half = l >> 5;
    const int row = bblk * 32 + r;

    for (int idx = t; idx < EXPERTS * 256; idx += 256)
        biasS[idx >> 8][idx & 255] = bias[(idx >> 8) * HIDDEN + ch * 256 + (idx & 255)];
    for (int idx = t; idx < 32 * 8; idx += 256)
        coeffS[idx >> 3][idx & 7] = coeff[(size_t)(bblk * 32 + (idx >> 3)) * 8 + (idx & 7)];
    __syncthreads();

    char* base = (char*)ApkNext + (size_t)bblk * NK * 1024;
    for (int jj = ch * 16 + wv; jj < ch * 16 + 16; jj += 4) {
        const int cb = jj * 16 + half * 8;
        float v[8];
        #pragma unroll
        for (int i = 0; i < 8; ++i) v[i] = 0.f;
        #pragma unroll
        for (int p = 0; p < NPART; ++p) {
            const float4* q = (const float4*)(P + ((size_t)p * BATCH + row) * HIDDEN + cb);
            const float4 a = q[0], b = q[1];
            v[0] += a.x; v[1] += a.y; v[2] += a.z; v[3] += a.w;
            v[4] += b.x; v[5] += b.y; v[6] += b.z; v[7] += b.w;
        }
        #pragma unroll
        for (int e = 0; e < EXPERTS; ++e) {
            const float cv = coeffS[r][e];
            #pragma unroll
            for (int i = 0; i < 8; ++i) v[i] = fmaf(cv, biasS[e][cb - ch * 256 + i], v[i]);
        }
        short8 hh;
        #pragma unroll
        for (int i = 0; i < 8; ++i) {
            const float hv = v[i] > 0.f ? v[i] : expm1f(v[i]);
            hh[i] = (short)f2h(hv);
        }
        *(short8*)(base + (size_t)(4 + jj) * 1024 + l * 16) = hh;
    }
}

// ---------------------------------------------------------------------------
// Final reduce: 8 partials + coeff-mixed bias, OUT=12
// ---------------------------------------------------------------------------
__global__ __launch_bounds__(256) void reduce_out_kernel(
    const float* __restrict__ P2, const float* __restrict__ coeff,
    const float* __restrict__ b2, float* __restrict__ out) {
    const int t = threadIdx.x;
    const int bblk = blockIdx.x;
    for (int idx = t; idx < 32 * ACTIONS; idx += 256) {
        const int r = idx / ACTIONS, n = idx % ACTIONS;
        const int row = bblk * 32 + r;
        float s = 0.f;
        #pragma unroll
        for (int p = 0; p < 8; ++p) s += P2[((size_t)p * BATCH + row) * 32 + n];
        const float* cf = coeff + (size_t)row * 8;
        #pragma unroll
        for (int e = 0; e < 8; ++e) s = fmaf(cf[e], b2[e * ACTIONS + n], s);
        out[(size_t)row * ACTIONS + n] = s;
    }
}

// ---------------------------------------------------------------------------
// MoE GEMM v6: single-plane f16, triple-buffered LDS A (gload_lds),
// 2-step-ahead prefetch with counted s_waitcnt vmcnt(12) + raw s_barrier
// (per-step in-flight = CPW gload_lds + EPB*4 B-loads = 12 for all configs).
// Tile 128 x (32*WN), waves 2 x WN, wave tile 64x32, 32x32x16 f16 MFMA.
// ---------------------------------------------------------------------------
template<int NK, int WN, int EPB, int OUTW, int GX, int GY, int GZ>
__global__ __launch_bounds__(128 * WN) void moe_gemm(
    const u16* __restrict__ Apk, const u16* __restrict__ Bpk,
    const float* __restrict__ coeff, float* __restrict__ P) {
    constexpr int TOT = NK / 4;           // K-steps of 64
    constexpr int NWAVE = 2 * WN;
    constexpr int CPW = 16 / NWAVE;       // A chunks per wave per step
    constexpr int CPX = GX / 8;

    __shared__ __align__(16) char As[3 * 16384];
    __shared__ float coeffT[EPB][128];

    const int t = threadIdx.x, wv = t >> 6, l = t & 63;
    const int wr = wv & 1, wc = wv >> 1;

    // XCD remap: contiguous x-chunk per XCD
    const int fid = blockIdx.x + GX * (blockIdx.y + GY * blockIdx.z);
    const int xcd = fid & 7, idx = fid >> 3;
    const int bx = xcd * CPX + (idx % CPX);
    const int yz = idx / CPX;
    const int by = yz % GY, bz = yz / GY;

    const int b0 = bx * 128;
    const int bblk0 = bx * 4;
    const int nblkg = by * WN + wc;
    const int part = bz;
    const int estart = part * EPB;

    for (int idx2 = t; idx2 < EPB * 128; idx2 += 128 * WN)
        coeffT[idx2 >> 7][idx2 & 127] =
            coeff[(size_t)(b0 + (idx2 & 127)) * EXPERTS + estart + (idx2 >> 7)];

    const char* Ab = (const char*)Apk;
    const char* Bbase[EPB];
    #pragma unroll
    for (int e = 0; e < EPB; ++e)
        Bbase[e] = (const char*)Bpk +
                   ((size_t)(nblkg * EXPERTS + estart + e) * NK) * 1024 + l * 16;

    f32x16 accE[EPB][2];
    #pragma unroll
    for (int e = 0; e < EPB; ++e) { accE[e][0] = (f32x16)0.f; accE[e][1] = (f32x16)0.f; }

    f16x8 breg[2][EPB][4];

    auto stageA = [&](int s) {
        char* dst = As + (s % 3) * 16384;
        #pragma unroll
        for (int q = 0; q < CPW; ++q) {
            const int cf = wv * CPW + q, bb = cf >> 2, kq = cf & 3;
            gload16(Ab + ((size_t)(bblk0 + bb) * NK + s * 4 + kq) * 1024 + l * 16,
                    dst + cf * 1024 + l * 16);
        }
    };

    __syncthreads();   // drain coeffT staging before pipeline accounting starts

    // prologue: 2-deep prefetch
    stageA(0);
    #pragma unroll
    for (int e = 0; e < EPB; ++e)
        #pragma unroll
        for (int q = 0; q < 4; ++q)
            breg[0][e][q] = *(const f16x8*)(Bbase[e] + (size_t)q * 1024);
    stageA(1);
    #pragma unroll
    for (int e = 0; e < EPB; ++e)
        #pragma unroll
        for (int q = 0; q < 4; ++q)
            breg[1][e][q] = *(const f16x8*)(Bbase[e] + (size_t)(4 + q) * 1024);

    #pragma unroll
    for (int s = 0; s < TOT; ++s) {
        // retire batch-for-s (A(s) stage + B(s)); keep later batches in flight
        if (s == TOT - 1) asm volatile("s_waitcnt vmcnt(0)" ::: "memory");
        else              asm volatile("s_waitcnt vmcnt(12)" ::: "memory");
        __builtin_amdgcn_sched_barrier(0);
        __builtin_amdgcn_s_barrier();
        __builtin_amdgcn_sched_barrier(0);

        if (s + 2 < TOT) stageA(s + 2);

        const char* buf = As + (s % 3) * 16384;
        f16x8 af0[4], af1[4];
        #pragma unroll
        for (int j = 0; j < 4; ++j) {
            af0[j] = *(const f16x8*)(buf + ((wr * 2 + 0) * 4 + j) * 1024 + l * 16);
            af1[j] = *(const f16x8*)(buf + ((wr * 2 + 1) * 4 + j) * 1024 + l * 16);
        }
        #pragma unroll
        for (int e = 0; e < EPB; ++e)
            #pragma unroll
            for (int j = 0; j < 4; ++j) {
                accE[e][0] = __builtin_amdgcn_mfma_f32_32x32x16_f16(af0[j], breg[s & 1][e][j], accE[e][0], 0, 0, 0);
                accE[e][1] = __builtin_amdgcn_mfma_f32_32x32x16_f16(af1[j], breg[s & 1][e][j], accE[e][1], 0, 0, 0);
            }
        // B prefetch for s+2 AFTER consumption of set s&1 (in-order issue -> WAR safe)
        if (s + 2 < TOT) {
            #pragma unroll
            for (int e = 0; e < EPB; ++e)
                #pragma unroll
                for (int q = 0; q < 4; ++q)
                    breg[s & 1][e][q] = *(const f16x8*)(Bbase[e] + (size_t)((s + 2) * 4 + q) * 1024);
        }
    }

    // epilogue: coeff fold + partial store
    const int ncol = nblkg * 32 + (l & 31);
    #pragma unroll
    for (int m = 0; m < 2; ++m) {
        #pragma unroll
        for (int g = 0; g < 16; ++g) {
            const int rloc = (g & 3) + 8 * (g >> 2) + 4 * (l >> 5);
            const int row = wr * 64 + m * 32 + rloc;
            float v = 0.f;
            #pragma unroll
            for (int e = 0; e < EPB; ++e) v = fmaf(coeffT[e][row], accE[e][m][g], v);
            P[((size_t)part * BATCH + b0 + row) * OUTW + ncol] = v;
        }
    }
}

// ---------------------------------------------------------------------------
extern "C" void kernel_launch(void* const* d_in, const int* in_sizes, int n_in,
                              void* d_out, int out_size, void* d_ws, size_t ws_size,
                              hipStream_t stream) {
    const float* z   = (const float*)d_in[0];
    const float* c   = (const float*)d_in[1];
    const float* w0  = (const float*)d_in[2];
    const float* b0  = (const float*)d_in[3];
    const float* w1  = (const float*)d_in[4];
    const float* b1  = (const float*)d_in[5];
    const float* w2  = (const float*)d_in[6];
    const float* b2  = (const float*)d_in[7];
    const float* gw0 = (const float*)d_in[8];
    const float* gb0 = (const float*)d_in[9];
    const float* gc0 = (const float*)d_in[10];
    const float* gw1 = (const float*)d_in[11];
    const float* gb1 = (const float*)d_in[12];
    const float* gc1 = (const float*)d_in[13];
    const float* gw2 = (const float*)d_in[14];
    const float* gb2 = (const float*)d_in[15];
    const float* gc2 = (const float*)d_in[16];
    float* out = (float*)d_out;

    char* p = (char*)d_ws;
    float* coeff = (float*)p;  p += (size_t)BATCH * EXPERTS * 4;
    float* gW0t  = (float*)p;  p += (size_t)GATE_H * IN_DIM * 4;
    float* gW1t  = (float*)p;  p += (size_t)GATE_H * GATE_H * 4;
    float* gW2t  = (float*)p;  p += (size_t)EXPERTS * GATE_H * 4;
    u16* Apk0 = (u16*)p;       p += (size_t)128 * 20 * 1024;      // 2.5 MB
    u16* Apk1 = (u16*)p;       p += (size_t)128 * 36 * 1024;      // 4.5 MB
    u16* Apk2 = (u16*)p;       p += (size_t)128 * 36 * 1024;      // 4.5 MB
    u16* Bpk0 = (u16*)p;       p += (size_t)16 * 8 * 20 * 1024;   // 2.5 MB
    u16* Bpk1 = (u16*)p;       p += (size_t)16 * 8 * 36 * 1024;   // 4.5 MB
    u16* Bpk2 = (u16*)p;       p += (size_t)8 * 36 * 1024;        // 0.3 MB
    float* P  = (float*)p;     p += (size_t)4 * BATCH * HIDDEN * 4;

    // gate
    scale_all_kernel<<<264, 64, 0, stream>>>(gw0, gc0, gW0t, gw1, gc1, gW1t,
                                             gw2, gc2, gW2t);
    gate_forward_v2<<<BATCH / GS, 128, 0, stream>>>(z, c, gW0t, gb0, gW1t, gb1,
                                                    gW2t, gb2, coeff);

    // packing
    wprep_kernel<IN_DIM, HIDDEN><<<dim3(EXPERTS, 16), 256, 0, stream>>>(w0, Bpk0);
    wprep_kernel<INTER,  HIDDEN><<<dim3(EXPERTS, 16), 256, 0, stream>>>(w1, Bpk1);
    wprep_kernel<INTER, ACTIONS><<<dim3(EXPERTS, 1), 256, 0, stream>>>(w2, Bpk2);
    apack_kernel<<<128, 256, 0, stream>>>(z, c, Apk0, Apk1, Apk2);

    // layer 0: NK=20, 5 steps
    moe_gemm<20, 2, 2, HIDDEN, 32, 8, 4><<<dim3(32, 8, 4), 256, 0, stream>>>(
        Apk0, Bpk0, coeff, P);
    reduce_pack_kernel<4><<<dim3(128, 2), 256, 0, stream>>>(P, coeff, b0, Apk1);

    // layer 1: NK=36, 9 steps
    moe_gemm<36, 2, 2, HIDDEN, 32, 8, 4><<<dim3(32, 8, 4), 256, 0, stream>>>(
        Apk1, Bpk1, coeff, P);
    reduce_pack_kernel<4><<<dim3(128, 2), 256, 0, stream>>>(P, coeff, b1, Apk2);

    // layer 2: NK=36, OUT padded 32, split-K 8
    moe_gemm<36, 1, 1, 32, 32, 1, 8><<<dim3(32, 1, 8), 128, 0, stream>>>(
        Apk2, Bpk2, coeff, P);
    reduce_out_kernel<<<128, 256, 0, stream>>>(P, coeff, b2, out);
}

// Round 7
// 149.638 us; speedup vs baseline: 7.0076x; 1.1295x over previous
//
#include <hip/hip_runtime.h>
#include <hip/hip_bf16.h>
#include <hip/hip_fp16.h>
#include <math.h>

#define BATCH 4096
#define INPUT_SIZE 256
#define LATENT 64
#define HIDDEN 512
#define ACTIONS 12
#define EXPERTS 8
#define GATE_H 128
#define IN_DIM (INPUT_SIZE + LATENT)   // 320
#define INTER (HIDDEN + LATENT)        // 576

typedef unsigned int u32;
typedef unsigned short u16;
typedef __attribute__((ext_vector_type(8))) short short8;
typedef __attribute__((ext_vector_type(8))) _Float16 f16x8;
typedef __attribute__((ext_vector_type(16))) float f32x16;

__device__ __forceinline__ u16 f2h(float x) { return __half_as_ushort(__float2half(x)); }
__device__ __forceinline__ float h2f(u16 u) { return __half2float(__ushort_as_half(u)); }

__device__ __forceinline__ void gload16(const void* g, void* lds) {
    __builtin_amdgcn_global_load_lds(
        (const __attribute__((address_space(1))) u32*)g,
        (__attribute__((address_space(3))) u32*)lds, 16, 0, 0);
}

// ---------------------------------------------------------------------------
// Fused Lipschitz row scaling for all 3 gate layers (transposed output)
// ---------------------------------------------------------------------------
__global__ void scale_all_kernel(
    const float* __restrict__ gw0, const float* __restrict__ gc0, float* __restrict__ W0t,
    const float* __restrict__ gw1, const float* __restrict__ gc1, float* __restrict__ W1t,
    const float* __restrict__ gw2, const float* __restrict__ gc2, float* __restrict__ W2t) {
    const int bid = blockIdx.x;
    const float* W; const float* cc; float* Wt; int cols, rows, row;
    if (bid < 128)      { W = gw0; cc = gc0; Wt = W0t; cols = IN_DIM; rows = GATE_H; row = bid; }
    else if (bid < 256) { W = gw1; cc = gc1; Wt = W1t; cols = GATE_H; rows = GATE_H; row = bid - 128; }
    else                { W = gw2; cc = gc2; Wt = W2t; cols = GATE_H; rows = EXPERTS; row = bid - 256; }
    const float* w = W + (size_t)row * cols;
    float s = 0.f;
    for (int i = threadIdx.x; i < cols; i += 64) s += fabsf(w[i]);
    #pragma unroll
    for (int off = 32; off > 0; off >>= 1) s += __shfl_down(s, off, 64);
    s = __shfl(s, 0, 64);
    const float cv = cc[0];
    const float lipc = (cv > 0.f) ? (cv + log1pf(expf(-cv))) : log1pf(expf(cv));
    const float scale = fminf(lipc / s, 1.0f);
    for (int i = threadIdx.x; i < cols; i += 64)
        Wt[(size_t)i * rows + row] = w[i] * scale;
}

// ---------------------------------------------------------------------------
// Gate MLP v3: 8 samples/block, 256 threads = (neuron, K-half).
// Coalesced transposed-weight loads, LDS broadcast for x/h, LDS partial
// reduce across the two K-halves. 512 blocks x 4 waves for latency hiding.
// ---------------------------------------------------------------------------
#define GS 8
__global__ __launch_bounds__(256) void gate_forward_v3(
    const float* __restrict__ z, const float* __restrict__ c,
    const float* __restrict__ W0t, const float* __restrict__ b0,
    const float* __restrict__ W1t, const float* __restrict__ b1,
    const float* __restrict__ W2t, const float* __restrict__ b2,
    float* __restrict__ coeff) {
    __shared__ float xs[GS][IN_DIM + 1];
    __shared__ float hs[GS][GATE_H + 1];
    __shared__ float hpart[GS][GATE_H];
    __shared__ float red[GS][EXPERTS];

    const int b8 = blockIdx.x * GS;
    const int t = threadIdx.x;
    const int n = t & 127, kh = t >> 7;

    for (int idx = t; idx < GS * IN_DIM; idx += 256) {
        const int s = idx / IN_DIM, i = idx - s * IN_DIM;
        xs[s][i] = (i < LATENT) ? z[(size_t)(b8 + s) * LATENT + i]
                                : c[(size_t)(b8 + s) * INPUT_SIZE + (i - LATENT)];
    }
    __syncthreads();

    // layer 0: 320 -> 128, K split 160/160 across kh
    {
        float acc[GS];
        #pragma unroll
        for (int s = 0; s < GS; ++s) acc[s] = kh ? 0.f : b0[n];
        const int i0 = kh * 160;
        #pragma unroll 8
        for (int i = i0; i < i0 + 160; ++i) {
            const float wv = W0t[(size_t)i * GATE_H + n];
            #pragma unroll
            for (int s = 0; s < GS; ++s) acc[s] = fmaf(xs[s][i], wv, acc[s]);
        }
        if (kh) {
            #pragma unroll
            for (int s = 0; s < GS; ++s) hpart[s][n] = acc[s];
        }
        __syncthreads();
        if (!kh) {
            #pragma unroll
            for (int s = 0; s < GS; ++s) {
                const float v = acc[s] + hpart[s][n];
                hs[s][n] = v > 0.f ? v : expm1f(v);
            }
        }
        __syncthreads();
    }
    // layer 1: 128 -> 128, K split 64/64
    {
        float acc[GS];
        #pragma unroll
        for (int s = 0; s < GS; ++s) acc[s] = kh ? 0.f : b1[n];
        const int i0 = kh * 64;
        #pragma unroll 8
        for (int i = i0; i < i0 + 64; ++i) {
            const float wv = W1t[(size_t)i * GATE_H + n];
            #pragma unroll
            for (int s = 0; s < GS; ++s) acc[s] = fmaf(hs[s][i], wv, acc[s]);
        }
        if (kh) {
            #pragma unroll
            for (int s = 0; s < GS; ++s) hpart[s][n] = acc[s];
        }
        __syncthreads();
        if (!kh) {
            #pragma unroll
            for (int s = 0; s < GS; ++s) {
                const float v = acc[s] + hpart[s][n];
                hpart[s][n] = v > 0.f ? v : expm1f(v);   // h2 lives in hpart
            }
        }
        __syncthreads();
    }
    // layer 2: 128 -> 8 logits; 64 threads = (s, e)
    if (t < GS * EXPERTS) {
        const int s = t >> 3, e = t & 7;
        float acc = b2[e];
        #pragma unroll 8
        for (int i = 0; i < GATE_H; ++i)
            acc = fmaf(hpart[s][i], W2t[(size_t)i * EXPERTS + e], acc);
        red[s][e] = acc;
    }
    __syncthreads();
    if (t < GS) {
        float m = red[t][0];
        #pragma unroll
        for (int i = 1; i < EXPERTS; ++i) m = fmaxf(m, red[t][i]);
        float e[EXPERTS];
        float sum = 0.f;
        #pragma unroll
        for (int i = 0; i < EXPERTS; ++i) { e[i] = expf(red[t][i] - m); sum += e[i]; }
        const float inv = 1.f / sum;
        #pragma unroll
        for (int i = 0; i < EXPERTS; ++i)
            coeff[(size_t)(b8 + t) * EXPERTS + i] = e[i] * inv;
    }
}

// ---------------------------------------------------------------------------
// B prep: w (E, IN, OUT) f32 -> frag-packed f16 single plane [NK ksubs]
// ---------------------------------------------------------------------------
template<int IN, int OUT>
__global__ __launch_bounds__(256) void wprep_kernel(const float* __restrict__ w,
                                                    u16* __restrict__ Bpk) {
    constexpr int NK = IN / 16;
    __shared__ float tile[4][16][33];
    const int t = threadIdx.x, wv = t >> 6, l = t & 63;
    const int e = blockIdx.x, nblk = blockIdx.y, n0 = nblk * 32;
    const int col = l & 31, half = l >> 5;
    char* base = (char*)Bpk + ((size_t)(nblk * EXPERTS + e) * NK) * 1024;

    for (int jj = wv; jj < NK; jj += 4) {
        #pragma unroll
        for (int i = 0; i < 8; ++i) {
            const int r = i * 2 + half;
            float v = 0.f;
            if (n0 + col < OUT) v = w[((size_t)e * IN + jj * 16 + r) * OUT + n0 + col];
            tile[wv][r][col] = v;
        }
        short8 hh;
        #pragma unroll
        for (int i = 0; i < 8; ++i)
            hh[i] = (short)f2h(tile[wv][half * 8 + i][col]);
        *(short8*)(base + (size_t)jj * 1024 + l * 16) = hh;
    }
}

// ---------------------------------------------------------------------------
// A prep: layer0 single plane (NK0=20) + z-parts (ksubs 0..3) of Apk1/Apk2
// ---------------------------------------------------------------------------
__global__ __launch_bounds__(256) void apack_kernel(const float* __restrict__ z,
                                                    const float* __restrict__ c,
                                                    u16* __restrict__ Apk0,
                                                    u16* __restrict__ Apk1,
                                                    u16* __restrict__ Apk2) {
    constexpr int NK0 = 20, NK1 = 36;
    const int t = threadIdx.x, wv = t >> 6, l = t & 63;
    const int bblk = blockIdx.x;
    const int r = l & 31, half = l >> 5;
    const int row = bblk * 32 + r;
    char* base0 = (char*)Apk0 + (size_t)bblk * NK0 * 1024;
    char* base1 = (char*)Apk1 + (size_t)bblk * NK1 * 1024;
    char* base2 = (char*)Apk2 + (size_t)bblk * NK1 * 1024;

    for (int jj = wv; jj < NK0; jj += 4) {
        const int k = jj * 16 + half * 8;
        const float* src = (k < LATENT) ? (z + (size_t)row * LATENT + k)
                                        : (c + (size_t)row * INPUT_SIZE + (k - LATENT));
        short8 hh;
        #pragma unroll
        for (int i = 0; i < 8; ++i) hh[i] = (short)f2h(src[i]);
        *(short8*)(base0 + (size_t)jj * 1024 + l * 16) = hh;
        if (jj < 4) {
            *(short8*)(base1 + (size_t)jj * 1024 + l * 16) = hh;
            *(short8*)(base2 + (size_t)jj * 1024 + l * 16) = hh;
        }
    }
}

// ---------------------------------------------------------------------------
// Reduce split-K partials + coeff-mixed bias + ELU -> packed next-A (f16)
// ---------------------------------------------------------------------------
template<int NPART>
__global__ __launch_bounds__(256) void reduce_pack_kernel(
    const float* __restrict__ P, const float* __restrict__ coeff,
    const float* __restrict__ bias, u16* __restrict__ ApkNext) {
    constexpr int NK = 36;
    __shared__ float biasS[EXPERTS][256];
    __shared__ float coeffS[32][9];
    const int t = threadIdx.x, wv = t >> 6, l = t & 63;
    const int bblk = blockIdx.x, ch = blockIdx.y;
    const int r = l & 31, half = l >> 5;
    const int row = bblk * 32 + r;

    for (int idx = t; idx < EXPERTS * 256; idx += 256)
        biasS[idx >> 8][idx & 255] = bias[(idx >> 8) * HIDDEN + ch * 256 + (idx & 255)];
    for (int idx = t; idx < 32 * 8; idx += 256)
        coeffS[idx >> 3][idx & 7] = coeff[(size_t)(bblk * 32 + (idx >> 3)) * 8 + (idx & 7)];
    __syncthreads();

    char* base = (char*)ApkNext + (size_t)bblk * NK * 1024;
    for (int jj = ch * 16 + wv; jj < ch * 16 + 16; jj += 4) {
        const int cb = jj * 16 + half * 8;
        float v[8];
        #pragma unroll
        for (int i = 0; i < 8; ++i) v[i] = 0.f;
        #pragma unroll
        for (int p = 0; p < NPART; ++p) {
            const float4* q = (const float4*)(P + ((size_t)p * BATCH + row) * HIDDEN + cb);
            const float4 a = q[0], b = q[1];
            v[0] += a.x; v[1] += a.y; v[2] += a.z; v[3] += a.w;
            v[4] += b.x; v[5] += b.y; v[6] += b.z; v[7] += b.w;
        }
        #pragma unroll
        for (int e = 0; e < EXPERTS; ++e) {
            const float cv = coeffS[r][e];
            #pragma unroll
            for (int i = 0; i < 8; ++i) v[i] = fmaf(cv, biasS[e][cb - ch * 256 + i], v[i]);
        }
        short8 hh;
        #pragma unroll
        for (int i = 0; i < 8; ++i) {
            const float hv = v[i] > 0.f ? v[i] : expm1f(v[i]);
            hh[i] = (short)f2h(hv);
        }
        *(short8*)(base + (size_t)(4 + jj) * 1024 + l * 16) = hh;
    }
}

// ---------------------------------------------------------------------------
// Final reduce: 8 partials + coeff-mixed bias, OUT=12
// ---------------------------------------------------------------------------
__global__ __launch_bounds__(256) void reduce_out_kernel(
    const float* __restrict__ P2, const float* __restrict__ coeff,
    const float* __restrict__ b2, float* __restrict__ out) {
    const int t = threadIdx.x;
    const int bblk = blockIdx.x;
    for (int idx = t; idx < 32 * ACTIONS; idx += 256) {
        const int r = idx / ACTIONS, n = idx % ACTIONS;
        const int row = bblk * 32 + r;
        float s = 0.f;
        #pragma unroll
        for (int p = 0; p < 8; ++p) s += P2[((size_t)p * BATCH + row) * 32 + n];
        const float* cf = coeff + (size_t)row * 8;
        #pragma unroll
        for (int e = 0; e < 8; ++e) s = fmaf(cf[e], b2[e * ACTIONS + n], s);
        out[(size_t)row * ACTIONS + n] = s;
    }
}

// ---------------------------------------------------------------------------
// MoE GEMM v6 (unchanged, verified): single-plane f16, triple-buffered LDS A,
// 2-step-ahead prefetch, counted s_waitcnt vmcnt(12) + raw s_barrier.
// ---------------------------------------------------------------------------
template<int NK, int WN, int EPB, int OUTW, int GX, int GY, int GZ>
__global__ __launch_bounds__(128 * WN) void moe_gemm(
    const u16* __restrict__ Apk, const u16* __restrict__ Bpk,
    const float* __restrict__ coeff, float* __restrict__ P) {
    constexpr int TOT = NK / 4;
    constexpr int NWAVE = 2 * WN;
    constexpr int CPW = 16 / NWAVE;
    constexpr int CPX = GX / 8;

    __shared__ __align__(16) char As[3 * 16384];
    __shared__ float coeffT[EPB][128];

    const int t = threadIdx.x, wv = t >> 6, l = t & 63;
    const int wr = wv & 1, wc = wv >> 1;

    const int fid = blockIdx.x + GX * (blockIdx.y + GY * blockIdx.z);
    const int xcd = fid & 7, idx = fid >> 3;
    const int bx = xcd * CPX + (idx % CPX);
    const int yz = idx / CPX;
    const int by = yz % GY, bz = yz / GY;

    const int b0 = bx * 128;
    const int bblk0 = bx * 4;
    const int nblkg = by * WN + wc;
    const int part = bz;
    const int estart = part * EPB;

    for (int idx2 = t; idx2 < EPB * 128; idx2 += 128 * WN)
        coeffT[idx2 >> 7][idx2 & 127] =
            coeff[(size_t)(b0 + (idx2 & 127)) * EXPERTS + estart + (idx2 >> 7)];

    const char* Ab = (const char*)Apk;
    const char* Bbase[EPB];
    #pragma unroll
    for (int e = 0; e < EPB; ++e)
        Bbase[e] = (const char*)Bpk +
                   ((size_t)(nblkg * EXPERTS + estart + e) * NK) * 1024 + l * 16;

    f32x16 accE[EPB][2];
    #pragma unroll
    for (int e = 0; e < EPB; ++e) { accE[e][0] = (f32x16)0.f; accE[e][1] = (f32x16)0.f; }

    f16x8 breg[2][EPB][4];

    auto stageA = [&](int s) {
        char* dst = As + (s % 3) * 16384;
        #pragma unroll
        for (int q = 0; q < CPW; ++q) {
            const int cf = wv * CPW + q, bb = cf >> 2, kq = cf & 3;
            gload16(Ab + ((size_t)(bblk0 + bb) * NK + s * 4 + kq) * 1024 + l * 16,
                    dst + cf * 1024 + l * 16);
        }
    };

    __syncthreads();

    stageA(0);
    #pragma unroll
    for (int e = 0; e < EPB; ++e)
        #pragma unroll
        for (int q = 0; q < 4; ++q)
            breg[0][e][q] = *(const f16x8*)(Bbase[e] + (size_t)q * 1024);
    stageA(1);
    #pragma unroll
    for (int e = 0; e < EPB; ++e)
        #pragma unroll
        for (int q = 0; q < 4; ++q)
            breg[1][e][q] = *(const f16x8*)(Bbase[e] + (size_t)(4 + q) * 1024);

    #pragma unroll
    for (int s = 0; s < TOT; ++s) {
        if (s == TOT - 1) asm volatile("s_waitcnt vmcnt(0)" ::: "memory");
        else              asm volatile("s_waitcnt vmcnt(12)" ::: "memory");
        __builtin_amdgcn_sched_barrier(0);
        __builtin_amdgcn_s_barrier();
        __builtin_amdgcn_sched_barrier(0);

        if (s + 2 < TOT) stageA(s + 2);

        const char* buf = As + (s % 3) * 16384;
        f16x8 af0[4], af1[4];
        #pragma unroll
        for (int j = 0; j < 4; ++j) {
            af0[j] = *(const f16x8*)(buf + ((wr * 2 + 0) * 4 + j) * 1024 + l * 16);
            af1[j] = *(const f16x8*)(buf + ((wr * 2 + 1) * 4 + j) * 1024 + l * 16);
        }
        #pragma unroll
        for (int e = 0; e < EPB; ++e)
            #pragma unroll
            for (int j = 0; j < 4; ++j) {
                accE[e][0] = __builtin_amdgcn_mfma_f32_32x32x16_f16(af0[j], breg[s & 1][e][j], accE[e][0], 0, 0, 0);
                accE[e][1] = __builtin_amdgcn_mfma_f32_32x32x16_f16(af1[j], breg[s & 1][e][j], accE[e][1], 0, 0, 0);
            }
        if (s + 2 < TOT) {
            #pragma unroll
            for (int e = 0; e < EPB; ++e)
                #pragma unroll
                for (int q = 0; q < 4; ++q)
                    breg[s & 1][e][q] = *(const f16x8*)(Bbase[e] + (size_t)((s + 2) * 4 + q) * 1024);
        }
    }

    const int ncol = nblkg * 32 + (l & 31);
    #pragma unroll
    for (int m = 0; m < 2; ++m) {
        #pragma unroll
        for (int g = 0; g < 16; ++g) {
            const int rloc = (g & 3) + 8 * (g >> 2) + 4 * (l >> 5);
            const int row = wr * 64 + m * 32 + rloc;
            float v = 0.f;
            #pragma unroll
            for (int e = 0; e < EPB; ++e) v = fmaf(coeffT[e][row], accE[e][m][g], v);
            P[((size_t)part * BATCH + b0 + row) * OUTW + ncol] = v;
        }
    }
}

// ---------------------------------------------------------------------------
extern "C" void kernel_launch(void* const* d_in, const int* in_sizes, int n_in,
                              void* d_out, int out_size, void* d_ws, size_t ws_size,
                              hipStream_t stream) {
    const float* z   = (const float*)d_in[0];
    const float* c   = (const float*)d_in[1];
    const float* w0  = (const float*)d_in[2];
    const float* b0  = (const float*)d_in[3];
    const float* w1  = (const float*)d_in[4];
    const float* b1  = (const float*)d_in[5];
    const float* w2  = (const float*)d_in[6];
    const float* b2  = (const float*)d_in[7];
    const float* gw0 = (const float*)d_in[8];
    const float* gb0 = (const float*)d_in[9];
    const float* gc0 = (const float*)d_in[10];
    const float* gw1 = (const float*)d_in[11];
    const float* gb1 = (const float*)d_in[12];
    const float* gc1 = (const float*)d_in[13];
    const float* gw2 = (const float*)d_in[14];
    const float* gb2 = (const float*)d_in[15];
    const float* gc2 = (const float*)d_in[16];
    float* out = (float*)d_out;

    char* p = (char*)d_ws;
    float* coeff = (float*)p;  p += (size_t)BATCH * EXPERTS * 4;
    float* gW0t  = (float*)p;  p += (size_t)GATE_H * IN_DIM * 4;
    float* gW1t  = (float*)p;  p += (size_t)GATE_H * GATE_H * 4;
    float* gW2t  = (float*)p;  p += (size_t)EXPERTS * GATE_H * 4;
    u16* Apk0 = (u16*)p;       p += (size_t)128 * 20 * 1024;
    u16* Apk1 = (u16*)p;       p += (size_t)128 * 36 * 1024;
    u16* Apk2 = (u16*)p;       p += (size_t)128 * 36 * 1024;
    u16* Bpk0 = (u16*)p;       p += (size_t)16 * 8 * 20 * 1024;
    u16* Bpk1 = (u16*)p;       p += (size_t)16 * 8 * 36 * 1024;
    u16* Bpk2 = (u16*)p;       p += (size_t)8 * 36 * 1024;
    float* P  = (float*)p;     p += (size_t)4 * BATCH * HIDDEN * 4;

    // gate
    scale_all_kernel<<<264, 64, 0, stream>>>(gw0, gc0, gW0t, gw1, gc1, gW1t,
                                             gw2, gc2, gW2t);
    gate_forward_v3<<<BATCH / GS, 256, 0, stream>>>(z, c, gW0t, gb0, gW1t, gb1,
                                                    gW2t, gb2, coeff);

    // packing
    wprep_kernel<IN_DIM, HIDDEN><<<dim3(EXPERTS, 16), 256, 0, stream>>>(w0, Bpk0);
    wprep_kernel<INTER,  HIDDEN><<<dim3(EXPERTS, 16), 256, 0, stream>>>(w1, Bpk1);
    wprep_kernel<INTER, ACTIONS><<<dim3(EXPERTS, 1), 256, 0, stream>>>(w2, Bpk2);
    apack_kernel<<<128, 256, 0, stream>>>(z, c, Apk0, Apk1, Apk2);

    // layer 0: NK=20, 5 steps
    moe_gemm<20, 2, 2, HIDDEN, 32, 8, 4><<<dim3(32, 8, 4), 256, 0, stream>>>(
        Apk0, Bpk0, coeff, P);
    reduce_pack_kernel<4><<<dim3(128, 2), 256, 0, stream>>>(P, coeff, b0, Apk1);

    // layer 1: NK=36, 9 steps
    moe_gemm<36, 2, 2, HIDDEN, 32, 8, 4><<<dim3(32, 8, 4), 256, 0, stream>>>(
        Apk1, Bpk1, coeff, P);
    reduce_pack_kernel<4><<<dim3(128, 2), 256, 0, stream>>>(P, coeff, b1, Apk2);

    // layer 2: NK=36, OUT padded 32, split-K 8
    moe_gemm<36, 1, 1, 32, 32, 1, 8><<<dim3(32, 1, 8), 128, 0, stream>>>(
        Apk2, Bpk2, coeff, P);
    reduce_out_kernel<<<128, 256, 0, stream>>>(P, coeff, b2, out);
}

// Round 8
// 120.878 us; speedup vs baseline: 8.6749x; 1.2379x over previous
//
#include <hip/hip_runtime.h>
#include <hip/hip_bf16.h>
#include <hip/hip_fp16.h>
#include <math.h>

#define BATCH 4096
#define INPUT_SIZE 256
#define LATENT 64
#define HIDDEN 512
#define ACTIONS 12
#define EXPERTS 8
#define GATE_H 128
#define IN_DIM (INPUT_SIZE + LATENT)   // 320
#define INTER (HIDDEN + LATENT)        // 576

typedef unsigned int u32;
typedef unsigned short u16;
typedef __attribute__((ext_vector_type(8))) short short8;
typedef __attribute__((ext_vector_type(8))) _Float16 f16x8;
typedef __attribute__((ext_vector_type(16))) float f32x16;

__device__ __forceinline__ u16 f2h(float x) { return __half_as_ushort(__float2half(x)); }
__device__ __forceinline__ float h2f(u16 u) { return __half2float(__ushort_as_half(u)); }

__device__ __forceinline__ void gload16(const void* g, void* lds) {
    __builtin_amdgcn_global_load_lds(
        (const __attribute__((address_space(1))) u32*)g,
        (__attribute__((address_space(3))) u32*)lds, 16, 0, 0);
}

// ---------------------------------------------------------------------------
// Fused Lipschitz row scaling for all 3 gate layers (transposed output)
// ---------------------------------------------------------------------------
__global__ void scale_all_kernel(
    const float* __restrict__ gw0, const float* __restrict__ gc0, float* __restrict__ W0t,
    const float* __restrict__ gw1, const float* __restrict__ gc1, float* __restrict__ W1t,
    const float* __restrict__ gw2, const float* __restrict__ gc2, float* __restrict__ W2t) {
    const int bid = blockIdx.x;
    const float* W; const float* cc; float* Wt; int cols, rows, row;
    if (bid < 128)      { W = gw0; cc = gc0; Wt = W0t; cols = IN_DIM; rows = GATE_H; row = bid; }
    else if (bid < 256) { W = gw1; cc = gc1; Wt = W1t; cols = GATE_H; rows = GATE_H; row = bid - 128; }
    else                { W = gw2; cc = gc2; Wt = W2t; cols = GATE_H; rows = EXPERTS; row = bid - 256; }
    const float* w = W + (size_t)row * cols;
    float s = 0.f;
    for (int i = threadIdx.x; i < cols; i += 64) s += fabsf(w[i]);
    #pragma unroll
    for (int off = 32; off > 0; off >>= 1) s += __shfl_down(s, off, 64);
    s = __shfl(s, 0, 64);
    const float cv = cc[0];
    const float lipc = (cv > 0.f) ? (cv + log1pf(expf(-cv))) : log1pf(expf(cv));
    const float scale = fminf(lipc / s, 1.0f);
    for (int i = threadIdx.x; i < cols; i += 64)
        Wt[(size_t)i * rows + row] = w[i] * scale;
}

// ---------------------------------------------------------------------------
// Gate MLP v4: 4 samples/block, 1024 blocks (16 waves/CU), 256 threads =
// (64 neuron-pairs x 4 K-quarters). float2 weight loads, LDS 4-way reduce.
// ---------------------------------------------------------------------------
#define GS 4
__global__ __launch_bounds__(256) void gate_forward_v4(
    const float* __restrict__ z, const float* __restrict__ c,
    const float* __restrict__ W0t, const float* __restrict__ b0,
    const float* __restrict__ W1t, const float* __restrict__ b1,
    const float* __restrict__ W2t, const float* __restrict__ b2,
    float* __restrict__ coeff) {
    __shared__ float xs[GS][IN_DIM + 2];
    __shared__ float hq[4][GS][GATE_H];
    __shared__ float h1[GS][GATE_H + 1];
    __shared__ float h2[GS][GATE_H + 1];
    __shared__ float red[GS][EXPERTS];

    const int b4 = blockIdx.x * GS;
    const int t = threadIdx.x;
    const int np = t & 63, kq = t >> 6;
    const int n0 = np * 2;

    for (int idx = t; idx < GS * IN_DIM; idx += 256) {
        const int s = idx / IN_DIM, i = idx - s * IN_DIM;
        xs[s][i] = (i < LATENT) ? z[(size_t)(b4 + s) * LATENT + i]
                                : c[(size_t)(b4 + s) * INPUT_SIZE + (i - LATENT)];
    }
    __syncthreads();

    // layer 0: 320 -> 128, K quartered (80 each)
    {
        float a0[GS], a1[GS];
        #pragma unroll
        for (int s = 0; s < GS; ++s) { a0[s] = 0.f; a1[s] = 0.f; }
        const int i0 = kq * 80;
        #pragma unroll 8
        for (int i = i0; i < i0 + 80; ++i) {
            const float2 wv = *(const float2*)(W0t + (size_t)i * GATE_H + n0);
            #pragma unroll
            for (int s = 0; s < GS; ++s) {
                a0[s] = fmaf(xs[s][i], wv.x, a0[s]);
                a1[s] = fmaf(xs[s][i], wv.y, a1[s]);
            }
        }
        #pragma unroll
        for (int s = 0; s < GS; ++s) { hq[kq][s][n0] = a0[s]; hq[kq][s][n0 + 1] = a1[s]; }
    }
    __syncthreads();
    if (kq == 0) {
        #pragma unroll
        for (int s = 0; s < GS; ++s)
            #pragma unroll
            for (int j = 0; j < 2; ++j) {
                const int n = n0 + j;
                const float v = b0[n] + hq[0][s][n] + hq[1][s][n] + hq[2][s][n] + hq[3][s][n];
                h1[s][n] = v > 0.f ? v : expm1f(v);
            }
    }
    __syncthreads();

    // layer 1: 128 -> 128, K quartered (32 each)
    {
        float a0[GS], a1[GS];
        #pragma unroll
        for (int s = 0; s < GS; ++s) { a0[s] = 0.f; a1[s] = 0.f; }
        const int i0 = kq * 32;
        #pragma unroll 8
        for (int i = i0; i < i0 + 32; ++i) {
            const float2 wv = *(const float2*)(W1t + (size_t)i * GATE_H + n0);
            #pragma unroll
            for (int s = 0; s < GS; ++s) {
                a0[s] = fmaf(h1[s][i], wv.x, a0[s]);
                a1[s] = fmaf(h1[s][i], wv.y, a1[s]);
            }
        }
        #pragma unroll
        for (int s = 0; s < GS; ++s) { hq[kq][s][n0] = a0[s]; hq[kq][s][n0 + 1] = a1[s]; }
    }
    __syncthreads();
    if (kq == 0) {
        #pragma unroll
        for (int s = 0; s < GS; ++s)
            #pragma unroll
            for (int j = 0; j < 2; ++j) {
                const int n = n0 + j;
                const float v = b1[n] + hq[0][s][n] + hq[1][s][n] + hq[2][s][n] + hq[3][s][n];
                h2[s][n] = v > 0.f ? v : expm1f(v);
            }
    }
    __syncthreads();

    // layer 2: 128 -> 8 logits (32 threads), then softmax
    if (t < GS * EXPERTS) {
        const int s = t >> 3, e = t & 7;
        float acc = b2[e];
        #pragma unroll 8
        for (int i = 0; i < GATE_H; ++i)
            acc = fmaf(h2[s][i], W2t[(size_t)i * EXPERTS + e], acc);
        red[s][e] = acc;
    }
    __syncthreads();
    if (t < GS) {
        float m = red[t][0];
        #pragma unroll
        for (int i = 1; i < EXPERTS; ++i) m = fmaxf(m, red[t][i]);
        float e[EXPERTS];
        float sum = 0.f;
        #pragma unroll
        for (int i = 0; i < EXPERTS; ++i) { e[i] = expf(red[t][i] - m); sum += e[i]; }
        const float inv = 1.f / sum;
        #pragma unroll
        for (int i = 0; i < EXPERTS; ++i)
            coeff[(size_t)(b4 + t) * EXPERTS + i] = e[i] * inv;
    }
}

// ---------------------------------------------------------------------------
// pack_all: fused weight packing (3 layers) + activation packing.
// grid (8, 49): y<16 -> wprep L0 (nblk=y); y<32 -> wprep L1 (nblk=y-16);
// y==32 -> wprep L2; y in [33,49) -> apack bblk = (y-33)*8 + x.
// wprep: w (E,IN,OUT) f32 -> frag-packed f16 single plane [NK ksubs].
// apack: layer0 A plane (NK0=20) + z-parts (ksubs 0..3) of Apk1/Apk2.
// ---------------------------------------------------------------------------
__global__ __launch_bounds__(256) void pack_all_kernel(
    const float* __restrict__ w0, const float* __restrict__ w1,
    const float* __restrict__ w2,
    const float* __restrict__ z, const float* __restrict__ c,
    u16* __restrict__ Bpk0, u16* __restrict__ Bpk1, u16* __restrict__ Bpk2,
    u16* __restrict__ Apk0, u16* __restrict__ Apk1, u16* __restrict__ Apk2) {
    const int t = threadIdx.x, wv = t >> 6, l = t & 63;
    const int x = blockIdx.x, y = blockIdx.y;

    if (y < 33) {
        // ---- wprep branch ----
        __shared__ float tile[4][16][33];
        const float* w; u16* Bpk; int IN, OUT, nblk;
        if (y < 16)      { w = w0; Bpk = Bpk0; IN = IN_DIM; OUT = HIDDEN;  nblk = y; }
        else if (y < 32) { w = w1; Bpk = Bpk1; IN = INTER;  OUT = HIDDEN;  nblk = y - 16; }
        else             { w = w2; Bpk = Bpk2; IN = INTER;  OUT = ACTIONS; nblk = 0; }
        const int NK = IN / 16;
        const int e = x, n0 = nblk * 32;
        const int col = l & 31, half = l >> 5;
        char* base = (char*)Bpk + ((size_t)(nblk * EXPERTS + e) * NK) * 1024;

        for (int jj = wv; jj < NK; jj += 4) {
            #pragma unroll
            for (int i = 0; i < 8; ++i) {
                const int r = i * 2 + half;
                float v = 0.f;
                if (n0 + col < OUT) v = w[((size_t)e * IN + jj * 16 + r) * OUT + n0 + col];
                tile[wv][r][col] = v;
            }
            short8 hh;
            #pragma unroll
            for (int i = 0; i < 8; ++i)
                hh[i] = (short)f2h(tile[wv][half * 8 + i][col]);
            *(short8*)(base + (size_t)jj * 1024 + l * 16) = hh;
        }
    } else {
        // ---- apack branch ----
        constexpr int NK0 = 20, NK1 = 36;
        const int bblk = (y - 33) * 8 + x;
        const int r = l & 31, half = l >> 5;
        const int row = bblk * 32 + r;
        char* base0 = (char*)Apk0 + (size_t)bblk * NK0 * 1024;
        char* base1 = (char*)Apk1 + (size_t)bblk * NK1 * 1024;
        char* base2 = (char*)Apk2 + (size_t)bblk * NK1 * 1024;

        for (int jj = wv; jj < NK0; jj += 4) {
            const int k = jj * 16 + half * 8;
            const float* src = (k < LATENT) ? (z + (size_t)row * LATENT + k)
                                            : (c + (size_t)row * INPUT_SIZE + (k - LATENT));
            short8 hh;
            #pragma unroll
            for (int i = 0; i < 8; ++i) hh[i] = (short)f2h(src[i]);
            *(short8*)(base0 + (size_t)jj * 1024 + l * 16) = hh;
            if (jj < 4) {
                *(short8*)(base1 + (size_t)jj * 1024 + l * 16) = hh;
                *(short8*)(base2 + (size_t)jj * 1024 + l * 16) = hh;
            }
        }
    }
}

// ---------------------------------------------------------------------------
// Reduce split-K partials + coeff-mixed bias + ELU -> packed next-A (f16)
// ---------------------------------------------------------------------------
template<int NPART>
__global__ __launch_bounds__(256) void reduce_pack_kernel(
    const float* __restrict__ P, const float* __restrict__ coeff,
    const float* __restrict__ bias, u16* __restrict__ ApkNext) {
    constexpr int NK = 36;
    __shared__ float biasS[EXPERTS][256];
    __shared__ float coeffS[32][9];
    const int t = threadIdx.x, wv = t >> 6, l = t & 63;
    const int bblk = blockIdx.x, ch = blockIdx.y;
    const int r = l & 31, half = l >> 5;
    const int row = bblk * 32 + r;

    for (int idx = t; idx < EXPERTS * 256; idx += 256)
        biasS[idx >> 8][idx & 255] = bias[(idx >> 8) * HIDDEN + ch * 256 + (idx & 255)];
    for (int idx = t; idx < 32 * 8; idx += 256)
        coeffS[idx >> 3][idx & 7] = coeff[(size_t)(bblk * 32 + (idx >> 3)) * 8 + (idx & 7)];
    __syncthreads();

    char* base = (char*)ApkNext + (size_t)bblk * NK * 1024;
    for (int jj = ch * 16 + wv; jj < ch * 16 + 16; jj += 4) {
        const int cb = jj * 16 + half * 8;
        float v[8];
        #pragma unroll
        for (int i = 0; i < 8; ++i) v[i] = 0.f;
        #pragma unroll
        for (int p = 0; p < NPART; ++p) {
            const float4* q = (const float4*)(P + ((size_t)p * BATCH + row) * HIDDEN + cb);
            const float4 a = q[0], b = q[1];
            v[0] += a.x; v[1] += a.y; v[2] += a.z; v[3] += a.w;
            v[4] += b.x; v[5] += b.y; v[6] += b.z; v[7] += b.w;
        }
        #pragma unroll
        for (int e = 0; e < EXPERTS; ++e) {
            const float cv = coeffS[r][e];
            #pragma unroll
            for (int i = 0; i < 8; ++i) v[i] = fmaf(cv, biasS[e][cb - ch * 256 + i], v[i]);
        }
        short8 hh;
        #pragma unroll
        for (int i = 0; i < 8; ++i) {
            const float hv = v[i] > 0.f ? v[i] : expm1f(v[i]);
            hh[i] = (short)f2h(hv);
        }
        *(short8*)(base + (size_t)(4 + jj) * 1024 + l * 16) = hh;
    }
}

// ---------------------------------------------------------------------------
// Final reduce: 8 partials + coeff-mixed bias, OUT=12
// ---------------------------------------------------------------------------
__global__ __launch_bounds__(256) void reduce_out_kernel(
    const float* __restrict__ P2, const float* __restrict__ coeff,
    const float* __restrict__ b2, float* __restrict__ out) {
    const int t = threadIdx.x;
    const int bblk = blockIdx.x;
    for (int idx = t; idx < 32 * ACTIONS; idx += 256) {
        const int r = idx / ACTIONS, n = idx % ACTIONS;
        const int row = bblk * 32 + r;
        float s = 0.f;
        #pragma unroll
        for (int p = 0; p < 8; ++p) s += P2[((size_t)p * BATCH + row) * 32 + n];
        const float* cf = coeff + (size_t)row * 8;
        #pragma unroll
        for (int e = 0; e < 8; ++e) s = fmaf(cf[e], b2[e * ACTIONS + n], s);
        out[(size_t)row * ACTIONS + n] = s;
    }
}

// ---------------------------------------------------------------------------
// MoE GEMM v6 (unchanged, verified): single-plane f16, triple-buffered LDS A,
// 2-step-ahead prefetch, counted s_waitcnt vmcnt(12) + raw s_barrier.
// ---------------------------------------------------------------------------
template<int NK, int WN, int EPB, int OUTW, int GX, int GY, int GZ>
__global__ __launch_bounds__(128 * WN) void moe_gemm(
    const u16* __restrict__ Apk, const u16* __restrict__ Bpk,
    const float* __restrict__ coeff, float* __restrict__ P) {
    constexpr int TOT = NK / 4;
    constexpr int NWAVE = 2 * WN;
    constexpr int CPW = 16 / NWAVE;
    constexpr int CPX = GX / 8;

    __shared__ __align__(16) char As[3 * 16384];
    __shared__ float coeffT[EPB][128];

    const int t = threadIdx.x, wv = t >> 6, l = t & 63;
    const int wr = wv & 1, wc = wv >> 1;

    const int fid = blockIdx.x + GX * (blockIdx.y + GY * blockIdx.z);
    const int xcd = fid & 7, idx = fid >> 3;
    const int bx = xcd * CPX + (idx % CPX);
    const int yz = idx / CPX;
    const int by = yz % GY, bz = yz / GY;

    const int b0 = bx * 128;
    const int bblk0 = bx * 4;
    const int nblkg = by * WN + wc;
    const int part = bz;
    const int estart = part * EPB;

    for (int idx2 = t; idx2 < EPB * 128; idx2 += 128 * WN)
        coeffT[idx2 >> 7][idx2 & 127] =
            coeff[(size_t)(b0 + (idx2 & 127)) * EXPERTS + estart + (idx2 >> 7)];

    const char* Ab = (const char*)Apk;
    const char* Bbase[EPB];
    #pragma unroll
    for (int e = 0; e < EPB; ++e)
        Bbase[e] = (const char*)Bpk +
                   ((size_t)(nblkg * EXPERTS + estart + e) * NK) * 1024 + l * 16;

    f32x16 accE[EPB][2];
    #pragma unroll
    for (int e = 0; e < EPB; ++e) { accE[e][0] = (f32x16)0.f; accE[e][1] = (f32x16)0.f; }

    f16x8 breg[2][EPB][4];

    auto stageA = [&](int s) {
        char* dst = As + (s % 3) * 16384;
        #pragma unroll
        for (int q = 0; q < CPW; ++q) {
            const int cf = wv * CPW + q, bb = cf >> 2, kq = cf & 3;
            gload16(Ab + ((size_t)(bblk0 + bb) * NK + s * 4 + kq) * 1024 + l * 16,
                    dst + cf * 1024 + l * 16);
        }
    };

    __syncthreads();

    stageA(0);
    #pragma unroll
    for (int e = 0; e < EPB; ++e)
        #pragma unroll
        for (int q = 0; q < 4; ++q)
            breg[0][e][q] = *(const f16x8*)(Bbase[e] + (size_t)q * 1024);
    stageA(1);
    #pragma unroll
    for (int e = 0; e < EPB; ++e)
        #pragma unroll
        for (int q = 0; q < 4; ++q)
            breg[1][e][q] = *(const f16x8*)(Bbase[e] + (size_t)(4 + q) * 1024);

    #pragma unroll
    for (int s = 0; s < TOT; ++s) {
        if (s == TOT - 1) asm volatile("s_waitcnt vmcnt(0)" ::: "memory");
        else              asm volatile("s_waitcnt vmcnt(12)" ::: "memory");
        __builtin_amdgcn_sched_barrier(0);
        __builtin_amdgcn_s_barrier();
        __builtin_amdgcn_sched_barrier(0);

        if (s + 2 < TOT) stageA(s + 2);

        const char* buf = As + (s % 3) * 16384;
        f16x8 af0[4], af1[4];
        #pragma unroll
        for (int j = 0; j < 4; ++j) {
            af0[j] = *(const f16x8*)(buf + ((wr * 2 + 0) * 4 + j) * 1024 + l * 16);
            af1[j] = *(const f16x8*)(buf + ((wr * 2 + 1) * 4 + j) * 1024 + l * 16);
        }
        #pragma unroll
        for (int e = 0; e < EPB; ++e)
            #pragma unroll
            for (int j = 0; j < 4; ++j) {
                accE[e][0] = __builtin_amdgcn_mfma_f32_32x32x16_f16(af0[j], breg[s & 1][e][j], accE[e][0], 0, 0, 0);
                accE[e][1] = __builtin_amdgcn_mfma_f32_32x32x16_f16(af1[j], breg[s & 1][e][j], accE[e][1], 0, 0, 0);
            }
        if (s + 2 < TOT) {
            #pragma unroll
            for (int e = 0; e < EPB; ++e)
                #pragma unroll
                for (int q = 0; q < 4; ++q)
                    breg[s & 1][e][q] = *(const f16x8*)(Bbase[e] + (size_t)((s + 2) * 4 + q) * 1024);
        }
    }

    const int ncol = nblkg * 32 + (l & 31);
    #pragma unroll
    for (int m = 0; m < 2; ++m) {
        #pragma unroll
        for (int g = 0; g < 16; ++g) {
            const int rloc = (g & 3) + 8 * (g >> 2) + 4 * (l >> 5);
            const int row = wr * 64 + m * 32 + rloc;
            float v = 0.f;
            #pragma unroll
            for (int e = 0; e < EPB; ++e) v = fmaf(coeffT[e][row], accE[e][m][g], v);
            P[((size_t)part * BATCH + b0 + row) * OUTW + ncol] = v;
        }
    }
}

// ---------------------------------------------------------------------------
extern "C" void kernel_launch(void* const* d_in, const int* in_sizes, int n_in,
                              void* d_out, int out_size, void* d_ws, size_t ws_size,
                              hipStream_t stream) {
    const float* z   = (const float*)d_in[0];
    const float* c   = (const float*)d_in[1];
    const float* w0  = (const float*)d_in[2];
    const float* b0  = (const float*)d_in[3];
    const float* w1  = (const float*)d_in[4];
    const float* b1  = (const float*)d_in[5];
    const float* w2  = (const float*)d_in[6];
    const float* b2  = (const float*)d_in[7];
    const float* gw0 = (const float*)d_in[8];
    const float* gb0 = (const float*)d_in[9];
    const float* gc0 = (const float*)d_in[10];
    const float* gw1 = (const float*)d_in[11];
    const float* gb1 = (const float*)d_in[12];
    const float* gc1 = (const float*)d_in[13];
    const float* gw2 = (const float*)d_in[14];
    const float* gb2 = (const float*)d_in[15];
    const float* gc2 = (const float*)d_in[16];
    float* out = (float*)d_out;

    char* p = (char*)d_ws;
    float* coeff = (float*)p;  p += (size_t)BATCH * EXPERTS * 4;
    float* gW0t  = (float*)p;  p += (size_t)GATE_H * IN_DIM * 4;
    float* gW1t  = (float*)p;  p += (size_t)GATE_H * GATE_H * 4;
    float* gW2t  = (float*)p;  p += (size_t)EXPERTS * GATE_H * 4;
    u16* Apk0 = (u16*)p;       p += (size_t)128 * 20 * 1024;
    u16* Apk1 = (u16*)p;       p += (size_t)128 * 36 * 1024;
    u16* Apk2 = (u16*)p;       p += (size_t)128 * 36 * 1024;
    u16* Bpk0 = (u16*)p;       p += (size_t)16 * 8 * 20 * 1024;
    u16* Bpk1 = (u16*)p;       p += (size_t)16 * 8 * 36 * 1024;
    u16* Bpk2 = (u16*)p;       p += (size_t)8 * 36 * 1024;
    float* P  = (float*)p;     p += (size_t)4 * BATCH * HIDDEN * 4;

    // gate weight scaling, then gate MLP (v4: 1024 blocks, float2 loads)
    scale_all_kernel<<<264, 64, 0, stream>>>(gw0, gc0, gW0t, gw1, gc1, gW1t,
                                             gw2, gc2, gW2t);
    gate_forward_v4<<<BATCH / GS, 256, 0, stream>>>(z, c, gW0t, gb0, gW1t, gb1,
                                                    gW2t, gb2, coeff);

    // fused packing (3x wprep + apack) in one launch
    pack_all_kernel<<<dim3(8, 49), 256, 0, stream>>>(w0, w1, w2, z, c,
                                                     Bpk0, Bpk1, Bpk2,
                                                     Apk0, Apk1, Apk2);

    // layer 0: NK=20, 5 steps
    moe_gemm<20, 2, 2, HIDDEN, 32, 8, 4><<<dim3(32, 8, 4), 256, 0, stream>>>(
        Apk0, Bpk0, coeff, P);
    reduce_pack_kernel<4><<<dim3(128, 2), 256, 0, stream>>>(P, coeff, b0, Apk1);

    // layer 1: NK=36, 9 steps
    moe_gemm<36, 2, 2, HIDDEN, 32, 8, 4><<<dim3(32, 8, 4), 256, 0, stream>>>(
        Apk1, Bpk1, coeff, P);
    reduce_pack_kernel<4><<<dim3(128, 2), 256, 0, stream>>>(P, coeff, b1, Apk2);

    // layer 2: NK=36, OUT padded 32, split-K 8
    moe_gemm<36, 1, 1, 32, 32, 1, 8><<<dim3(32, 1, 8), 128, 0, stream>>>(
        Apk2, Bpk2, coeff, P);
    reduce_out_kernel<<<128, 256, 0, stream>>>(P, coeff, b2, out);
}